// Round 1
// baseline (727.263 us; speedup 1.0000x reference)
//
#include <hip/hip_runtime.h>
#include <hip/hip_bf16.h>
#include <math.h>

// CrossPairMemory round 1: full bf16-MFMA pipeline.
// Phases: transpose/convert weights -> prep(mean+softmax) -> PV GEMMs ->
// GEMM1 -> LN+GELU -> GEMM2 -> per-pair GEMM + LN epilogue.

#define B_SZ  4096
#define NPAIR 28
#define PDIM  128
#define MDIM  256
#define NSLOT 64
#define DALL  3584   // NPAIR*PDIM
#define DCAT  7168   // 2*DALL

typedef __hip_bfloat16 bf16;
typedef __attribute__((ext_vector_type(8))) short bf16x8;  // 8 bf16 = 4 VGPRs
typedef __attribute__((ext_vector_type(4))) float f32x4;

__device__ __forceinline__ void async_copy16(void* lds, const void* g) {
  __builtin_amdgcn_global_load_lds((__attribute__((address_space(1))) void*)g,
                                   (__attribute__((address_space(3))) void*)lds,
                                   16, 0, 0);
}

// ---------------- transpose + fp32->bf16 convert: out[c][r] = in[r][c] -----
__global__ __launch_bounds__(256)
void tconv_kernel(const float* __restrict__ in, bf16* __restrict__ out,
                  int R, int C, int inBatch, int outBatch) {
  __shared__ float tile[32][33];
  const int tid = threadIdx.x;
  const int tx = tid & 31, ty = tid >> 5;  // ty 0..7
  const long ib = (long)blockIdx.z * inBatch;
  const long ob = (long)blockIdx.z * outBatch;
  const int c0 = blockIdx.x * 32, r0 = blockIdx.y * 32;
#pragma unroll
  for (int i = 0; i < 4; ++i)
    tile[ty + i * 8][tx] = in[ib + (long)(r0 + ty + i * 8) * C + c0 + tx];
  __syncthreads();
#pragma unroll
  for (int i = 0; i < 4; ++i)
    out[ob + (long)(c0 + ty + i * 8) * R + r0 + tx] =
        __float2bfloat16(tile[tx][ty + i * 8]);
}

// ---------------- prep: pair mean -> q, softmax scores, ps->bf16 ----------
__global__ __launch_bounds__(256)
void prep_kernel(const float* __restrict__ ps, const float* __restrict__ mac,
                 const float* __restrict__ pkeys, const float* __restrict__ mkeys,
                 bf16* __restrict__ psb, bf16* __restrict__ attn_p,
                 bf16* __restrict__ attn_m) {
  const int b = blockIdx.x, tid = threadIdx.x;
  __shared__ float q[PDIM];
  __shared__ float mrow[MDIM];
  const float* prow = ps + (long)b * DALL;
  if (tid < MDIM) mrow[tid] = mac[(long)b * MDIM + tid];
  if (tid < PDIM) {
    float s = 0.f;
#pragma unroll
    for (int p = 0; p < NPAIR; ++p) s += prow[p * PDIM + tid];
    q[tid] = s * (1.f / NPAIR);
  }
  for (int i = tid; i < DALL; i += 256)
    psb[(long)b * DALL + i] = __float2bfloat16(prow[i]);
  __syncthreads();
  const int wid = tid >> 6, lane = tid & 63;
  if (wid == 0) {
    float sc = 0.f;
    const float* kr = pkeys + lane * PDIM;
    for (int d = 0; d < PDIM; ++d) sc += q[d] * kr[d];
    sc *= 0.08838834764831845f;  // 1/sqrt(128)
    float mx = sc;
#pragma unroll
    for (int m = 32; m; m >>= 1) mx = fmaxf(mx, __shfl_xor(mx, m));
    float e = expf(sc - mx);
    float ssum = e;
#pragma unroll
    for (int m = 32; m; m >>= 1) ssum += __shfl_xor(ssum, m);
    attn_p[(long)b * NSLOT + lane] = __float2bfloat16(e / ssum);
  } else if (wid == 1) {
    float sc = 0.f;
    const float* kr = mkeys + lane * MDIM;
    for (int d = 0; d < MDIM; ++d) sc += mrow[d] * kr[d];
    sc *= 0.0625f;  // 1/sqrt(256)
    float mx = sc;
#pragma unroll
    for (int m = 32; m; m >>= 1) mx = fmaxf(mx, __shfl_xor(mx, m));
    float e = expf(sc - mx);
    float ssum = e;
#pragma unroll
    for (int m = 32; m; m >>= 1) ssum += __shfl_xor(ssum, m);
    attn_m[(long)b * NSLOT + lane] = __float2bfloat16(e / ssum);
  }
}

// ---------------- generic bf16 GEMM: C = A(MxK) * Bt(NxK)^T [+bias] -------
// 128x128 tile, BK=32, 4 waves in 2x2, each wave 64x64 via 4x4 16x16x32 MFMA.
template <int OUT_BF16, int ADD_BIAS>
__global__ __launch_bounds__(256)
void gemm_bt(const bf16* __restrict__ A, int lda, const bf16* __restrict__ Bt,
             void* __restrict__ Cout, int ldc, int col_off,
             const float* __restrict__ bias, int K) {
  __shared__ __align__(16) bf16 sA[128 * 32];
  __shared__ __align__(16) bf16 sB[128 * 32];
  const int tid = threadIdx.x;
  const int wid = tid >> 6, lane = tid & 63;
  const int lr = lane & 15, lk = lane >> 4;
  const int col0 = blockIdx.x * 128, row0 = blockIdx.y * 128;
  const int wrow = (wid >> 1) * 64, wcol = (wid & 1) * 64;
  const int ea = tid * 8;
  const int ra = ea >> 5, ca = ea & 31;  // within-tile row/col for staging

  f32x4 acc[4][4];
  const f32x4 zero = {0.f, 0.f, 0.f, 0.f};
#pragma unroll
  for (int m = 0; m < 4; ++m)
#pragma unroll
    for (int n = 0; n < 4; ++n) acc[m][n] = zero;

  const long aBase = (long)row0 * lda;
  const long bBase = (long)col0 * K;
  char* sAb = (char*)sA;
  char* sBb = (char*)sB;
  const int wOff = wid * 1024;  // bytes: 64 lanes * 16B

  for (int kt = 0; kt < K; kt += 32) {
    __syncthreads();
#pragma unroll
    for (int i = 0; i < 2; ++i) {
      async_copy16(sAb + i * 4096 + wOff,
                   A + aBase + (long)(ra + i * 64) * lda + kt + ca);
      async_copy16(sBb + i * 4096 + wOff,
                   Bt + bBase + (long)(ra + i * 64) * K + kt + ca);
    }
    __syncthreads();
    bf16x8 af[4], bfr[4];
    const bf16x8* pA = (const bf16x8*)sA;
    const bf16x8* pB = (const bf16x8*)sB;
#pragma unroll
    for (int m = 0; m < 4; ++m) af[m] = pA[(wrow + m * 16 + lr) * 4 + lk];
#pragma unroll
    for (int n = 0; n < 4; ++n) bfr[n] = pB[(wcol + n * 16 + lr) * 4 + lk];
#pragma unroll
    for (int m = 0; m < 4; ++m)
#pragma unroll
      for (int n = 0; n < 4; ++n)
        acc[m][n] =
            __builtin_amdgcn_mfma_f32_16x16x32_bf16(af[m], bfr[n], acc[m][n], 0, 0, 0);
  }
  // epilogue: D row=(lane>>4)*4+j, col=lane&15 within each 16x16 frag
#pragma unroll
  for (int m = 0; m < 4; ++m) {
#pragma unroll
    for (int n = 0; n < 4; ++n) {
      const int gcl = col0 + wcol + n * 16 + lr;
      const float bia = ADD_BIAS ? bias[gcl] : 0.f;
#pragma unroll
      for (int j = 0; j < 4; ++j) {
        const int gr = row0 + wrow + m * 16 + lk * 4 + j;
        const float v = acc[m][n][j] + bia;
        const long off = (long)gr * ldc + col_off + gcl;
        if (OUT_BF16)
          ((bf16*)Cout)[off] = __float2bfloat16(v);
        else
          ((float*)Cout)[off] = v;
      }
    }
  }
}

// ---------------- LayerNorm + exact GELU, fp32 in -> bf16 out -------------
__global__ __launch_bounds__(256)
void ln_gelu_kernel(const float* __restrict__ h, const float* __restrict__ g,
                    const float* __restrict__ bb, bf16* __restrict__ h2) {
  const int row = blockIdx.x, tid = threadIdx.x;
  const float* x = h + (long)row * DALL;
  float v[14];
  float s1 = 0.f, s2 = 0.f;
#pragma unroll
  for (int i = 0; i < 14; ++i) {
    v[i] = x[i * 256 + tid];
    s1 += v[i];
    s2 += v[i] * v[i];
  }
#pragma unroll
  for (int m = 32; m; m >>= 1) {
    s1 += __shfl_xor(s1, m);
    s2 += __shfl_xor(s2, m);
  }
  __shared__ float r1[4], r2[4];
  const int wid = tid >> 6, lane = tid & 63;
  if (lane == 0) {
    r1[wid] = s1;
    r2[wid] = s2;
  }
  __syncthreads();
  s1 = r1[0] + r1[1] + r1[2] + r1[3];
  s2 = r2[0] + r2[1] + r2[2] + r2[3];
  const float mean = s1 * (1.f / DALL);
  const float var = s2 * (1.f / DALL) - mean * mean;
  const float rstd = rsqrtf(var + 1e-5f);
#pragma unroll
  for (int i = 0; i < 14; ++i) {
    const int c = i * 256 + tid;
    const float y = (v[i] - mean) * rstd * g[c] + bb[c];
    const float ge = 0.5f * y * (1.f + erff(y * 0.7071067811865475f));
    h2[(long)row * DALL + c] = __float2bfloat16(ge);
  }
}

// ---------------- per-pair GEMM (K=256) + LayerNorm epilogue --------------
// waves arranged 4x1: each wave owns 32 rows x all 128 cols -> LN is
// a 16-lane shfl reduction (row r held by lanes with same lane>>4).
__global__ __launch_bounds__(256)
void pair_final(const bf16* __restrict__ psb, const bf16* __restrict__ fusedb,
                const bf16* __restrict__ pwT, const float* __restrict__ pb,
                const float* __restrict__ lng, const float* __restrict__ lnb,
                float* __restrict__ out) {
  __shared__ __align__(16) bf16 sA[128 * 32];
  __shared__ __align__(16) bf16 sB[128 * 32];
  const int tid = threadIdx.x, wid = tid >> 6, lane = tid & 63;
  const int lr = lane & 15, lk = lane >> 4;
  const int p = blockIdx.y, row0 = blockIdx.x * 128;
  const int ea = tid * 8, ra = ea >> 5, ca = ea & 31;

  f32x4 acc[2][8];
  const f32x4 zero = {0.f, 0.f, 0.f, 0.f};
#pragma unroll
  for (int m = 0; m < 2; ++m)
#pragma unroll
    for (int n = 0; n < 8; ++n) acc[m][n] = zero;

  const bf16* pwp = pwT + (long)p * (PDIM * MDIM);  // 128 x 256, N x K
  char* sAb = (char*)sA;
  char* sBb = (char*)sB;
  const int wOff = wid * 1024;

  for (int kt = 0; kt < MDIM; kt += 32) {
    __syncthreads();
    const bf16* Asrc = (kt < PDIM) ? psb : fusedb;  // uniform per kt
    const int kc = kt & (PDIM - 1);
#pragma unroll
    for (int i = 0; i < 2; ++i) {
      async_copy16(sAb + i * 4096 + wOff,
                   Asrc + (long)(row0 + ra + i * 64) * DALL + p * PDIM + kc + ca);
      async_copy16(sBb + i * 4096 + wOff, pwp + (ra + i * 64) * MDIM + kt + ca);
    }
    __syncthreads();
    bf16x8 af[2], bfr[8];
    const bf16x8* pA = (const bf16x8*)sA;
    const bf16x8* pB = (const bf16x8*)sB;
#pragma unroll
    for (int m = 0; m < 2; ++m) af[m] = pA[(wid * 32 + m * 16 + lr) * 4 + lk];
#pragma unroll
    for (int n = 0; n < 8; ++n) bfr[n] = pB[(n * 16 + lr) * 4 + lk];
#pragma unroll
    for (int m = 0; m < 2; ++m)
#pragma unroll
      for (int n = 0; n < 8; ++n)
        acc[m][n] =
            __builtin_amdgcn_mfma_f32_16x16x32_bf16(af[m], bfr[n], acc[m][n], 0, 0, 0);
  }
  // LN epilogue
  float g_[8], b_[8], pb_[8];
#pragma unroll
  for (int n = 0; n < 8; ++n) {
    const int c = n * 16 + lr;
    g_[n] = lng[p * PDIM + c];
    b_[n] = lnb[p * PDIM + c];
    pb_[n] = pb[p * PDIM + c];
  }
#pragma unroll
  for (int m = 0; m < 2; ++m) {
#pragma unroll
    for (int j = 0; j < 4; ++j) {
      float vv[8];
      float s1 = 0.f, s2 = 0.f;
#pragma unroll
      for (int n = 0; n < 8; ++n) {
        vv[n] = acc[m][n][j] + pb_[n];
        s1 += vv[n];
        s2 += vv[n] * vv[n];
      }
#pragma unroll
      for (int msk = 1; msk <= 8; msk <<= 1) {
        s1 += __shfl_xor(s1, msk);
        s2 += __shfl_xor(s2, msk);
      }
      const float mean = s1 * (1.f / 128.f);
      const float var = s2 * (1.f / 128.f) - mean * mean;
      const float rstd = rsqrtf(var + 1e-5f);
      const int gr = row0 + wid * 32 + m * 16 + lk * 4 + j;
      float* orow = out + ((long)gr * NPAIR + p) * PDIM;
#pragma unroll
      for (int n = 0; n < 8; ++n)
        orow[n * 16 + lr] = (vv[n] - mean) * rstd * g_[n] + b_[n];
    }
  }
}

// ---------------------------------------------------------------------------
extern "C" void kernel_launch(void* const* d_in, const int* in_sizes, int n_in,
                              void* d_out, int out_size, void* d_ws, size_t ws_size,
                              hipStream_t stream) {
  (void)in_sizes; (void)n_in; (void)out_size; (void)ws_size;
  const float* ps   = (const float*)d_in[0];
  const float* mac  = (const float*)d_in[1];
  const float* pkey = (const float*)d_in[2];
  const float* pval = (const float*)d_in[3];
  const float* mkey = (const float*)d_in[4];
  const float* mval = (const float*)d_in[5];
  const float* w1   = (const float*)d_in[6];
  const float* b1   = (const float*)d_in[7];
  const float* lng1 = (const float*)d_in[8];
  const float* lnb1 = (const float*)d_in[9];
  const float* w2   = (const float*)d_in[10];
  const float* b2   = (const float*)d_in[11];
  const float* pw   = (const float*)d_in[12];
  const float* pb   = (const float*)d_in[13];
  const float* plng = (const float*)d_in[14];
  const float* plnb = (const float*)d_in[15];
  float* out = (float*)d_out;

  char* w = (char*)d_ws;
  size_t off = 0;
  auto carve = [&](size_t bytes) {
    char* pp = w + off;
    off += (bytes + 255) & ~(size_t)255;
    return pp;
  };
  bf16* psb   = (bf16*)carve((size_t)B_SZ * DALL * 2);       // 29.4 MB
  bf16* w1t   = (bf16*)carve((size_t)DALL * DCAT * 2);       // 51.4 MB
  bf16* w2t   = (bf16*)carve((size_t)DALL * DALL * 2);       // 25.7 MB
  bf16* pvT   = (bf16*)carve((size_t)DALL * NSLOT * 2);
  bf16* mvT   = (bf16*)carve((size_t)DALL * NSLOT * 2);
  bf16* pwTb  = (bf16*)carve((size_t)NPAIR * PDIM * MDIM * 2);
  bf16* atp   = (bf16*)carve((size_t)B_SZ * NSLOT * 2);
  bf16* atm   = (bf16*)carve((size_t)B_SZ * NSLOT * 2);
  bf16* hin   = (bf16*)carve((size_t)B_SZ * DCAT * 2);       // 58.7 MB
  float* hpre = (float*)carve((size_t)B_SZ * DALL * 4);      // 58.7 MB
  // lifetime aliases (stream-ordered: safe):
  bf16* h2     = w1t;          // h2 written after GEMM1 consumed w1t
  bf16* fusedb = (bf16*)hpre;  // fused written after ln_gelu consumed hpre

  // weight converts/transposes (N x K bf16 layouts)
  tconv_kernel<<<dim3(DALL / 32, DCAT / 32, 1), 256, 0, stream>>>(w1, w1t, DCAT, DALL, 0, 0);
  tconv_kernel<<<dim3(DALL / 32, DALL / 32, 1), 256, 0, stream>>>(w2, w2t, DALL, DALL, 0, 0);
  tconv_kernel<<<dim3(DALL / 32, NSLOT / 32, 1), 256, 0, stream>>>(pval, pvT, NSLOT, DALL, 0, 0);
  tconv_kernel<<<dim3(DALL / 32, NSLOT / 32, 1), 256, 0, stream>>>(mval, mvT, NSLOT, DALL, 0, 0);
  tconv_kernel<<<dim3(PDIM / 32, MDIM / 32, NPAIR), 256, 0, stream>>>(
      pw, pwTb, MDIM, PDIM, MDIM * PDIM, MDIM * PDIM);
  // mean + softmax + ps->bf16
  prep_kernel<<<dim3(B_SZ), 256, 0, stream>>>(ps, mac, pkey, mkey, psb, atp, atm);
  // PV GEMMs -> h_in = [pair_corr | macro_corr] bf16
  gemm_bt<1, 0><<<dim3(DALL / 128, B_SZ / 128), 256, 0, stream>>>(
      atp, NSLOT, pvT, hin, DCAT, 0, nullptr, NSLOT);
  gemm_bt<1, 0><<<dim3(DALL / 128, B_SZ / 128), 256, 0, stream>>>(
      atm, NSLOT, mvT, hin, DCAT, DALL, nullptr, NSLOT);
  // GEMM1 + bias -> fp32 h_pre
  gemm_bt<0, 1><<<dim3(DALL / 128, B_SZ / 128), 256, 0, stream>>>(
      hin, DCAT, w1t, hpre, DALL, 0, b1, DCAT);
  // LN + exact GELU -> bf16 h2
  ln_gelu_kernel<<<dim3(B_SZ), 256, 0, stream>>>(hpre, lng1, lnb1, h2);
  // GEMM2 + bias -> bf16 fused
  gemm_bt<1, 1><<<dim3(DALL / 128, B_SZ / 128), 256, 0, stream>>>(
      h2, DALL, w2t, fusedb, DALL, 0, b2, DALL);
  // per-pair GEMM + LN -> out
  pair_final<<<dim3(B_SZ / 128, NPAIR), 256, 0, stream>>>(
      psb, fusedb, pwTb, pb, plng, plnb, out);
}

// Round 2
// 484.748 us; speedup vs baseline: 1.5003x; 1.5003x over previous
//
#include <hip/hip_runtime.h>
#include <hip/hip_bf16.h>
#include <math.h>

// CrossPairMemory round 2: GEMM1/GEMM2 moved to 256x256 8-phase template
// (T2 LDS xor-swizzle + T3/T4 counted vmcnt + T5 setprio). Rest unchanged.

#define B_SZ  4096
#define NPAIR 28
#define PDIM  128
#define MDIM  256
#define NSLOT 64
#define DALL  3584
#define DCAT  7168

typedef __hip_bfloat16 bf16;
typedef __attribute__((ext_vector_type(8))) short bf16x8;
typedef __attribute__((ext_vector_type(4))) float f32x4;

#define BARRIER() asm volatile("s_barrier" ::: "memory")
#define LGKM0()   asm volatile("s_waitcnt lgkmcnt(0)" ::: "memory")
#define VMCNT4()  asm volatile("s_waitcnt vmcnt(4)" ::: "memory")
#define VMCNT0()  asm volatile("s_waitcnt vmcnt(0)" ::: "memory")

__device__ __forceinline__ void async_copy16(void* lds, const void* g) {
  __builtin_amdgcn_global_load_lds((__attribute__((address_space(1))) void*)g,
                                   (__attribute__((address_space(3))) void*)lds,
                                   16, 0, 0);
}

// ============== 256x256x64 8-phase GEMM: C = A(MxK) * Bt(NxK)^T [+bias] ====
// 512 threads = 8 waves (2M x 4N). Per wave 128x64 output = 8x4 16x16 frags.
// LDS 128KB: A dbuf 2x32KB @0, B dbuf 2x32KB @64KB. Tile stored [256][64]bf16
// row-major (128B rows, 8x 16B granules); swizzle: granule ^= (row&7), applied
// on the pre-swizzled GLOBAL source column (gload_lds writes linearly) and on
// the ds_read address. Phases per K-tile:
//  p0: ds a[m0-3] + b[n0-1]; stage A(t+1)h0 -> other buf; BAR;LGKM0; MFMA Qll
//  p1: ds b[n2-3];           stage A(t+1)h1;              BAR;LGKM0; MFMA Qlh
//  p2: ds a[m4-7];           stage B(t+2)h0 -> this buf;  BAR;LGKM0; MFMA Qhl
//  p3:                       stage B(t+2)h1; VMCNT(4); BAR; MFMA Qhh
// vmcnt(4) leaves the 2 newest half-tiles (B(t+2)) in flight; everything
// older (= all of tile t+1) has landed.
template <int OUT_BF16, int ADD_BIAS>
__global__ __launch_bounds__(512, 2)
void gemm8(const bf16* __restrict__ A, int lda, const bf16* __restrict__ Bt,
           int ldb, void* __restrict__ Cout, int ldc,
           const float* __restrict__ bias, int K, int nbx) {
  __shared__ __align__(16) char smem[131072];
  const int tid = threadIdx.x;
  const int wid = tid >> 6, lane = tid & 63;
  const int lr = lane & 15, lk = lane >> 4;
  const int wm = wid >> 2, wn = wid & 3;
  // XCD-bijective swizzle (gridDim.x % 8 == 0 by construction)
  const int nwg = gridDim.x, cpx = nwg >> 3;
  const int swz = ((int)blockIdx.x & 7) * cpx + ((int)blockIdx.x >> 3);
  const int bx = swz % nbx, by = swz / nbx;
  const int col0 = bx * 256, row0 = by * 256;

  char* sA = smem;            // [2][16KB half0][16KB half1]
  char* sB = smem + 65536;

  // staging geometry: 512 thr, 2 issues each per half-tile (16KB).
  const int srow = tid >> 3;                 // 0..63
  const int sg = (tid & 7) ^ (srow & 7);     // pre-swizzled source granule
  const bf16* aStage = A + (long)(row0 + srow) * lda + sg * 8;
  const bf16* bStage = Bt + (long)(col0 + srow) * ldb + sg * 8;
  const int wOff = wid << 10;

  const int NT = K >> 6;

  // frag read byte-offsets (within one 32KB buffer): row*128 + (g^(lr&7))*16
  const int sx = lr & 7;
  const int arow = wm * 128 + lr;
  const int brow = wn * 64 + lr;

  f32x4 acc[8][4];
  const f32x4 zero = {0.f, 0.f, 0.f, 0.f};
#pragma unroll
  for (int m = 0; m < 8; ++m)
#pragma unroll
    for (int n = 0; n < 4; ++n) acc[m][n] = zero;

  // ---- prologue: B(0), A(0) -> buf0; B(1) -> buf1. 12 issues/wave.
#pragma unroll
  for (int h = 0; h < 2; ++h) {
    const bf16* g = bStage + (long)h * 128 * ldb;          // tile 0
    char* d = sB + h * 16384 + wOff;
    async_copy16(d, g);
    async_copy16(d + 8192, g + 64 * ldb);
  }
#pragma unroll
  for (int h = 0; h < 2; ++h) {
    const bf16* g = aStage + (long)h * 128 * lda;
    char* d = sA + h * 16384 + wOff;
    async_copy16(d, g);
    async_copy16(d + 8192, g + 64 * lda);
  }
#pragma unroll
  for (int h = 0; h < 2; ++h) {
    const bf16* g = bStage + (long)h * 128 * ldb + 64;     // tile 1
    char* d = sB + 32768 + h * 16384 + wOff;
    async_copy16(d, g);
    async_copy16(d + 8192, g + 64 * ldb);
  }
  VMCNT4();  // tile 0 (oldest 8 issues) landed
  BARRIER();

  bf16x8 af[4][2], bl[2][2], bh[2][2];

  for (int t = 0; t < NT; ++t) {
    const int buf = t & 1;
    char* cA = sA + buf * 32768;
    char* cB = sB + buf * 32768;
    char* nA = sA + (buf ^ 1) * 32768;

    // ---------------- p0: a-low + b-low reads; stage A(t+1) h0
#pragma unroll
    for (int m = 0; m < 4; ++m)
#pragma unroll
      for (int kk = 0; kk < 2; ++kk)
        af[m][kk] = *(const bf16x8*)(cA + (arow + m * 16) * 128 +
                                     ((((kk << 2) | lk) ^ sx) << 4));
#pragma unroll
    for (int n = 0; n < 2; ++n)
#pragma unroll
      for (int kk = 0; kk < 2; ++kk)
        bl[n][kk] = *(const bf16x8*)(cB + (brow + n * 16) * 128 +
                                     ((((kk << 2) | lk) ^ sx) << 4));
    if (t + 1 < NT) {
      const bf16* g = aStage + (long)(t + 1) * 64;
      async_copy16(nA + wOff, g);
      async_copy16(nA + 8192 + wOff, g + 64 * lda);
    }
    BARRIER();
    LGKM0();
    __builtin_amdgcn_s_setprio(1);
#pragma unroll
    for (int m = 0; m < 4; ++m)
#pragma unroll
      for (int n = 0; n < 2; ++n)
#pragma unroll
        for (int kk = 0; kk < 2; ++kk)
          acc[m][n] = __builtin_amdgcn_mfma_f32_16x16x32_bf16(
              af[m][kk], bl[n][kk], acc[m][n], 0, 0, 0);
    __builtin_amdgcn_s_setprio(0);
    BARRIER();

    // ---------------- p1: b-high reads; stage A(t+1) h1
#pragma unroll
    for (int n = 0; n < 2; ++n)
#pragma unroll
      for (int kk = 0; kk < 2; ++kk)
        bh[n][kk] = *(const bf16x8*)(cB + (brow + (n + 2) * 16) * 128 +
                                     ((((kk << 2) | lk) ^ sx) << 4));
    if (t + 1 < NT) {
      const bf16* g = aStage + (long)128 * lda + (long)(t + 1) * 64;
      async_copy16(nA + 16384 + wOff, g);
      async_copy16(nA + 16384 + 8192 + wOff, g + 64 * lda);
    }
    BARRIER();
    LGKM0();
    __builtin_amdgcn_s_setprio(1);
#pragma unroll
    for (int m = 0; m < 4; ++m)
#pragma unroll
      for (int n = 0; n < 2; ++n)
#pragma unroll
        for (int kk = 0; kk < 2; ++kk)
          acc[m][n + 2] = __builtin_amdgcn_mfma_f32_16x16x32_bf16(
              af[m][kk], bh[n][kk], acc[m][n + 2], 0, 0, 0);
    __builtin_amdgcn_s_setprio(0);
    BARRIER();

    // ---------------- p2: a-high reads; stage B(t+2) h0 (into THIS buf's B)
#pragma unroll
    for (int m = 0; m < 4; ++m)
#pragma unroll
      for (int kk = 0; kk < 2; ++kk)
        af[m][kk] = *(const bf16x8*)(cA + (arow + (m + 4) * 16) * 128 +
                                     ((((kk << 2) | lk) ^ sx) << 4));
    if (t + 2 < NT) {
      const bf16* g = bStage + (long)(t + 2) * 64;
      async_copy16(cB + wOff, g);
      async_copy16(cB + 8192 + wOff, g + 64 * ldb);
    }
    BARRIER();
    LGKM0();
    __builtin_amdgcn_s_setprio(1);
#pragma unroll
    for (int m = 0; m < 4; ++m)
#pragma unroll
      for (int n = 0; n < 2; ++n)
#pragma unroll
        for (int kk = 0; kk < 2; ++kk)
          acc[m + 4][n] = __builtin_amdgcn_mfma_f32_16x16x32_bf16(
              af[m][kk], bl[n][kk], acc[m + 4][n], 0, 0, 0);
    __builtin_amdgcn_s_setprio(0);
    BARRIER();

    // ---------------- p3: stage B(t+2) h1; counted vmcnt; last quadrant
    if (t + 2 < NT) {
      const bf16* g = bStage + (long)128 * ldb + (long)(t + 2) * 64;
      async_copy16(cB + 16384 + wOff, g);
      async_copy16(cB + 16384 + 8192 + wOff, g + 64 * ldb);
      VMCNT4();
    } else {
      VMCNT0();
    }
    BARRIER();
    __builtin_amdgcn_s_setprio(1);
#pragma unroll
    for (int m = 0; m < 4; ++m)
#pragma unroll
      for (int n = 0; n < 2; ++n)
#pragma unroll
        for (int kk = 0; kk < 2; ++kk)
          acc[m + 4][n + 2] = __builtin_amdgcn_mfma_f32_16x16x32_bf16(
              af[m][kk], bh[n][kk], acc[m + 4][n + 2], 0, 0, 0);
    __builtin_amdgcn_s_setprio(0);
    BARRIER();
  }

  // ---- epilogue
#pragma unroll
  for (int m = 0; m < 8; ++m) {
#pragma unroll
    for (int n = 0; n < 4; ++n) {
      const int gc = col0 + wn * 64 + n * 16 + lr;
      const float bia = ADD_BIAS ? bias[gc] : 0.f;
#pragma unroll
      for (int j = 0; j < 4; ++j) {
        const int gr = row0 + wm * 128 + m * 16 + lk * 4 + j;
        const float v = acc[m][n][j] + bia;
        const long off = (long)gr * ldc + gc;
        if (OUT_BF16)
          ((bf16*)Cout)[off] = __float2bfloat16(v);
        else
          ((float*)Cout)[off] = v;
      }
    }
  }
}

// ---------------- transpose + fp32->bf16 convert ---------------------------
__global__ __launch_bounds__(256)
void tconv_kernel(const float* __restrict__ in, bf16* __restrict__ out,
                  int R, int C, int inBatch, int outBatch) {
  __shared__ float tile[32][33];
  const int tid = threadIdx.x;
  const int tx = tid & 31, ty = tid >> 5;
  const long ib = (long)blockIdx.z * inBatch;
  const long ob = (long)blockIdx.z * outBatch;
  const int c0 = blockIdx.x * 32, r0 = blockIdx.y * 32;
#pragma unroll
  for (int i = 0; i < 4; ++i)
    tile[ty + i * 8][tx] = in[ib + (long)(r0 + ty + i * 8) * C + c0 + tx];
  __syncthreads();
#pragma unroll
  for (int i = 0; i < 4; ++i)
    out[ob + (long)(c0 + ty + i * 8) * R + r0 + tx] =
        __float2bfloat16(tile[tx][ty + i * 8]);
}

// ---------------- prep: pair mean -> q, softmax scores, ps->bf16 ----------
__global__ __launch_bounds__(256)
void prep_kernel(const float* __restrict__ ps, const float* __restrict__ mac,
                 const float* __restrict__ pkeys, const float* __restrict__ mkeys,
                 bf16* __restrict__ psb, bf16* __restrict__ attn_p,
                 bf16* __restrict__ attn_m) {
  const int b = blockIdx.x, tid = threadIdx.x;
  __shared__ float q[PDIM];
  __shared__ float mrow[MDIM];
  const float* prow = ps + (long)b * DALL;
  if (tid < MDIM) mrow[tid] = mac[(long)b * MDIM + tid];
  if (tid < PDIM) {
    float s = 0.f;
#pragma unroll
    for (int p = 0; p < NPAIR; ++p) s += prow[p * PDIM + tid];
    q[tid] = s * (1.f / NPAIR);
  }
  for (int i = tid; i < DALL; i += 256)
    psb[(long)b * DALL + i] = __float2bfloat16(prow[i]);
  __syncthreads();
  const int wid = tid >> 6, lane = tid & 63;
  if (wid == 0) {
    float sc = 0.f;
    const float* kr = pkeys + lane * PDIM;
    for (int d = 0; d < PDIM; ++d) sc += q[d] * kr[d];
    sc *= 0.08838834764831845f;
    float mx = sc;
#pragma unroll
    for (int m = 32; m; m >>= 1) mx = fmaxf(mx, __shfl_xor(mx, m));
    float e = expf(sc - mx);
    float ssum = e;
#pragma unroll
    for (int m = 32; m; m >>= 1) ssum += __shfl_xor(ssum, m);
    attn_p[(long)b * NSLOT + lane] = __float2bfloat16(e / ssum);
  } else if (wid == 1) {
    float sc = 0.f;
    const float* kr = mkeys + lane * MDIM;
    for (int d = 0; d < MDIM; ++d) sc += mrow[d] * kr[d];
    sc *= 0.0625f;
    float mx = sc;
#pragma unroll
    for (int m = 32; m; m >>= 1) mx = fmaxf(mx, __shfl_xor(mx, m));
    float e = expf(sc - mx);
    float ssum = e;
#pragma unroll
    for (int m = 32; m; m >>= 1) ssum += __shfl_xor(ssum, m);
    attn_m[(long)b * NSLOT + lane] = __float2bfloat16(e / ssum);
  }
}

// ---------------- small-K bf16 GEMM (PV): 128x128, 2-barrier --------------
template <int OUT_BF16, int ADD_BIAS>
__global__ __launch_bounds__(256)
void gemm_bt(const bf16* __restrict__ A, int lda, const bf16* __restrict__ Bt,
             void* __restrict__ Cout, int ldc, int col_off,
             const float* __restrict__ bias, int K) {
  __shared__ __align__(16) bf16 sA[128 * 32];
  __shared__ __align__(16) bf16 sB[128 * 32];
  const int tid = threadIdx.x;
  const int wid = tid >> 6, lane = tid & 63;
  const int lr = lane & 15, lk = lane >> 4;
  const int col0 = blockIdx.x * 128, row0 = blockIdx.y * 128;
  const int wrow = (wid >> 1) * 64, wcol = (wid & 1) * 64;
  const int ea = tid * 8;
  const int ra = ea >> 5, ca = ea & 31;

  f32x4 acc[4][4];
  const f32x4 zero = {0.f, 0.f, 0.f, 0.f};
#pragma unroll
  for (int m = 0; m < 4; ++m)
#pragma unroll
    for (int n = 0; n < 4; ++n) acc[m][n] = zero;

  const long aBase = (long)row0 * lda;
  const long bBase = (long)col0 * K;
  char* sAb = (char*)sA;
  char* sBb = (char*)sB;
  const int wOff = wid * 1024;

  for (int kt = 0; kt < K; kt += 32) {
    __syncthreads();
#pragma unroll
    for (int i = 0; i < 2; ++i) {
      async_copy16(sAb + i * 4096 + wOff,
                   A + aBase + (long)(ra + i * 64) * lda + kt + ca);
      async_copy16(sBb + i * 4096 + wOff,
                   Bt + bBase + (long)(ra + i * 64) * K + kt + ca);
    }
    __syncthreads();
    bf16x8 af[4], bfr[4];
    const bf16x8* pA = (const bf16x8*)sA;
    const bf16x8* pB = (const bf16x8*)sB;
#pragma unroll
    for (int m = 0; m < 4; ++m) af[m] = pA[(wrow + m * 16 + lr) * 4 + lk];
#pragma unroll
    for (int n = 0; n < 4; ++n) bfr[n] = pB[(wcol + n * 16 + lr) * 4 + lk];
#pragma unroll
    for (int m = 0; m < 4; ++m)
#pragma unroll
      for (int n = 0; n < 4; ++n)
        acc[m][n] =
            __builtin_amdgcn_mfma_f32_16x16x32_bf16(af[m], bfr[n], acc[m][n], 0, 0, 0);
  }
#pragma unroll
  for (int m = 0; m < 4; ++m) {
#pragma unroll
    for (int n = 0; n < 4; ++n) {
      const int gcl = col0 + wcol + n * 16 + lr;
      const float bia = ADD_BIAS ? bias[gcl] : 0.f;
#pragma unroll
      for (int j = 0; j < 4; ++j) {
        const int gr = row0 + wrow + m * 16 + lk * 4 + j;
        const float v = acc[m][n][j] + bia;
        const long off = (long)gr * ldc + col_off + gcl;
        if (OUT_BF16)
          ((bf16*)Cout)[off] = __float2bfloat16(v);
        else
          ((float*)Cout)[off] = v;
      }
    }
  }
}

// ---------------- LayerNorm + exact GELU, fp32 in -> bf16 out -------------
__global__ __launch_bounds__(256)
void ln_gelu_kernel(const float* __restrict__ h, const float* __restrict__ g,
                    const float* __restrict__ bb, bf16* __restrict__ h2) {
  const int row = blockIdx.x, tid = threadIdx.x;
  const float* x = h + (long)row * DALL;
  float v[14];
  float s1 = 0.f, s2 = 0.f;
#pragma unroll
  for (int i = 0; i < 14; ++i) {
    v[i] = x[i * 256 + tid];
    s1 += v[i];
    s2 += v[i] * v[i];
  }
#pragma unroll
  for (int m = 32; m; m >>= 1) {
    s1 += __shfl_xor(s1, m);
    s2 += __shfl_xor(s2, m);
  }
  __shared__ float r1[4], r2[4];
  const int wid = tid >> 6, lane = tid & 63;
  if (lane == 0) {
    r1[wid] = s1;
    r2[wid] = s2;
  }
  __syncthreads();
  s1 = r1[0] + r1[1] + r1[2] + r1[3];
  s2 = r2[0] + r2[1] + r2[2] + r2[3];
  const float mean = s1 * (1.f / DALL);
  const float var = s2 * (1.f / DALL) - mean * mean;
  const float rstd = rsqrtf(var + 1e-5f);
#pragma unroll
  for (int i = 0; i < 14; ++i) {
    const int c = i * 256 + tid;
    const float y = (v[i] - mean) * rstd * g[c] + bb[c];
    const float ge = 0.5f * y * (1.f + erff(y * 0.7071067811865475f));
    h2[(long)row * DALL + c] = __float2bfloat16(ge);
  }
}

// ---------------- per-pair GEMM (K=256) + LayerNorm epilogue --------------
__global__ __launch_bounds__(256)
void pair_final(const bf16* __restrict__ psb, const bf16* __restrict__ fusedb,
                const bf16* __restrict__ pwT, const float* __restrict__ pb,
                const float* __restrict__ lng, const float* __restrict__ lnb,
                float* __restrict__ out) {
  __shared__ __align__(16) bf16 sA[128 * 32];
  __shared__ __align__(16) bf16 sB[128 * 32];
  const int tid = threadIdx.x, wid = tid >> 6, lane = tid & 63;
  const int lr = lane & 15, lk = lane >> 4;
  const int p = blockIdx.y, row0 = blockIdx.x * 128;
  const int ea = tid * 8, ra = ea >> 5, ca = ea & 31;

  f32x4 acc[2][8];
  const f32x4 zero = {0.f, 0.f, 0.f, 0.f};
#pragma unroll
  for (int m = 0; m < 2; ++m)
#pragma unroll
    for (int n = 0; n < 8; ++n) acc[m][n] = zero;

  const bf16* pwp = pwT + (long)p * (PDIM * MDIM);
  char* sAb = (char*)sA;
  char* sBb = (char*)sB;
  const int wOff = wid * 1024;

  for (int kt = 0; kt < MDIM; kt += 32) {
    __syncthreads();
    const bf16* Asrc = (kt < PDIM) ? psb : fusedb;
    const int kc = kt & (PDIM - 1);
#pragma unroll
    for (int i = 0; i < 2; ++i) {
      async_copy16(sAb + i * 4096 + wOff,
                   Asrc + (long)(row0 + ra + i * 64) * DALL + p * PDIM + kc + ca);
      async_copy16(sBb + i * 4096 + wOff, pwp + (ra + i * 64) * MDIM + kt + ca);
    }
    __syncthreads();
    bf16x8 af[2], bfr[8];
    const bf16x8* pA = (const bf16x8*)sA;
    const bf16x8* pB = (const bf16x8*)sB;
#pragma unroll
    for (int m = 0; m < 2; ++m) af[m] = pA[(wid * 32 + m * 16 + lr) * 4 + lk];
#pragma unroll
    for (int n = 0; n < 8; ++n) bfr[n] = pB[(n * 16 + lr) * 4 + lk];
#pragma unroll
    for (int m = 0; m < 2; ++m)
#pragma unroll
      for (int n = 0; n < 8; ++n)
        acc[m][n] =
            __builtin_amdgcn_mfma_f32_16x16x32_bf16(af[m], bfr[n], acc[m][n], 0, 0, 0);
  }
  float g_[8], b_[8], pb_[8];
#pragma unroll
  for (int n = 0; n < 8; ++n) {
    const int c = n * 16 + lr;
    g_[n] = lng[p * PDIM + c];
    b_[n] = lnb[p * PDIM + c];
    pb_[n] = pb[p * PDIM + c];
  }
#pragma unroll
  for (int m = 0; m < 2; ++m) {
#pragma unroll
    for (int j = 0; j < 4; ++j) {
      float vv[8];
      float s1 = 0.f, s2 = 0.f;
#pragma unroll
      for (int n = 0; n < 8; ++n) {
        vv[n] = acc[m][n][j] + pb_[n];
        s1 += vv[n];
        s2 += vv[n] * vv[n];
      }
#pragma unroll
      for (int msk = 1; msk <= 8; msk <<= 1) {
        s1 += __shfl_xor(s1, msk);
        s2 += __shfl_xor(s2, msk);
      }
      const float mean = s1 * (1.f / 128.f);
      const float var = s2 * (1.f / 128.f) - mean * mean;
      const float rstd = rsqrtf(var + 1e-5f);
      const int gr = row0 + wid * 32 + m * 16 + lk * 4 + j;
      float* orow = out + ((long)gr * NPAIR + p) * PDIM;
#pragma unroll
      for (int n = 0; n < 8; ++n)
        orow[n * 16 + lr] = (vv[n] - mean) * rstd * g_[n] + b_[n];
    }
  }
}

// ---------------------------------------------------------------------------
extern "C" void kernel_launch(void* const* d_in, const int* in_sizes, int n_in,
                              void* d_out, int out_size, void* d_ws, size_t ws_size,
                              hipStream_t stream) {
  (void)in_sizes; (void)n_in; (void)out_size; (void)ws_size;
  const float* ps   = (const float*)d_in[0];
  const float* mac  = (const float*)d_in[1];
  const float* pkey = (const float*)d_in[2];
  const float* pval = (const float*)d_in[3];
  const float* mkey = (const float*)d_in[4];
  const float* mval = (const float*)d_in[5];
  const float* w1   = (const float*)d_in[6];
  const float* b1   = (const float*)d_in[7];
  const float* lng1 = (const float*)d_in[8];
  const float* lnb1 = (const float*)d_in[9];
  const float* w2   = (const float*)d_in[10];
  const float* b2   = (const float*)d_in[11];
  const float* pw   = (const float*)d_in[12];
  const float* pb   = (const float*)d_in[13];
  const float* plng = (const float*)d_in[14];
  const float* plnb = (const float*)d_in[15];
  float* out = (float*)d_out;

  char* w = (char*)d_ws;
  size_t off = 0;
  auto carve = [&](size_t bytes) {
    char* pp = w + off;
    off += (bytes + 255) & ~(size_t)255;
    return pp;
  };
  bf16* psb   = (bf16*)carve((size_t)B_SZ * DALL * 2);
  bf16* w1t   = (bf16*)carve((size_t)DALL * DCAT * 2);
  bf16* w2t   = (bf16*)carve((size_t)DALL * DALL * 2);
  bf16* pvT   = (bf16*)carve((size_t)DALL * NSLOT * 2);
  bf16* mvT   = (bf16*)carve((size_t)DALL * NSLOT * 2);
  bf16* pwTb  = (bf16*)carve((size_t)NPAIR * PDIM * MDIM * 2);
  bf16* atp   = (bf16*)carve((size_t)B_SZ * NSLOT * 2);
  bf16* atm   = (bf16*)carve((size_t)B_SZ * NSLOT * 2);
  bf16* hin   = (bf16*)carve((size_t)B_SZ * DCAT * 2);
  float* hpre = (float*)carve((size_t)B_SZ * DALL * 4);
  bf16* h2     = w1t;          // alias: written after GEMM1 consumed w1t
  bf16* fusedb = (bf16*)hpre;  // alias: written after ln_gelu consumed hpre

  tconv_kernel<<<dim3(DALL / 32, DCAT / 32, 1), 256, 0, stream>>>(w1, w1t, DCAT, DALL, 0, 0);
  tconv_kernel<<<dim3(DALL / 32, DALL / 32, 1), 256, 0, stream>>>(w2, w2t, DALL, DALL, 0, 0);
  tconv_kernel<<<dim3(DALL / 32, NSLOT / 32, 1), 256, 0, stream>>>(pval, pvT, NSLOT, DALL, 0, 0);
  tconv_kernel<<<dim3(DALL / 32, NSLOT / 32, 1), 256, 0, stream>>>(mval, mvT, NSLOT, DALL, 0, 0);
  tconv_kernel<<<dim3(PDIM / 32, MDIM / 32, NPAIR), 256, 0, stream>>>(
      pw, pwTb, MDIM, PDIM, MDIM * PDIM, MDIM * PDIM);
  prep_kernel<<<dim3(B_SZ), 256, 0, stream>>>(ps, mac, pkey, mkey, psb, atp, atm);
  gemm_bt<1, 0><<<dim3(DALL / 128, B_SZ / 128), 256, 0, stream>>>(
      atp, NSLOT, pvT, hin, DCAT, 0, nullptr, NSLOT);
  gemm_bt<1, 0><<<dim3(DALL / 128, B_SZ / 128), 256, 0, stream>>>(
      atm, NSLOT, mvT, hin, DCAT, DALL, nullptr, NSLOT);
  // GEMM1: (4096 x 7168) @ (7168 x 3584) -> fp32 hpre.  grid 14*16=224 (%8==0)
  gemm8<0, 1><<<dim3((DALL / 256) * (B_SZ / 256)), 512, 0, stream>>>(
      hin, DCAT, w1t, DCAT, hpre, DALL, b1, DCAT, DALL / 256);
  ln_gelu_kernel<<<dim3(B_SZ), 256, 0, stream>>>(hpre, lng1, lnb1, h2);
  // GEMM2: (4096 x 3584) @ (3584 x 3584) -> bf16 fused
  gemm8<1, 1><<<dim3((DALL / 256) * (B_SZ / 256)), 512, 0, stream>>>(
      h2, DALL, w2t, DALL, fusedb, DALL, b2, DALL, DALL / 256);
  pair_final<<<dim3(B_SZ / 128, NPAIR), 256, 0, stream>>>(
      psb, fusedb, pwTb, pb, plng, plnb, out);
}

// Round 3
// 474.696 us; speedup vs baseline: 1.5321x; 1.0212x over previous
//
#include <hip/hip_runtime.h>
#include <hip/hip_bf16.h>
#include <math.h>

// CrossPairMemory round 3: gemm8 drops per-phase LGKM0 + pre-MFMA barrier
// (compiler emits fine-grained lgkmcnt -> ds_read/MFMA overlap); vmcnt(4)
// moved after P3 MFMA. GEMM1 now outputs bf16 (ln_gelu reads bf16).

#define B_SZ  4096
#define NPAIR 28
#define PDIM  128
#define MDIM  256
#define NSLOT 64
#define DALL  3584
#define DCAT  7168

typedef __hip_bfloat16 bf16;
typedef __attribute__((ext_vector_type(8))) short bf16x8;
typedef __attribute__((ext_vector_type(4))) float f32x4;

#define BARRIER() asm volatile("s_barrier" ::: "memory")
#define VMCNT4()  asm volatile("s_waitcnt vmcnt(4)" ::: "memory")
#define VMCNT0()  asm volatile("s_waitcnt vmcnt(0)" ::: "memory")

__device__ __forceinline__ void async_copy16(void* lds, const void* g) {
  __builtin_amdgcn_global_load_lds((__attribute__((address_space(1))) void*)g,
                                   (__attribute__((address_space(3))) void*)lds,
                                   16, 0, 0);
}

// ============== 256x256x64 4-phase GEMM: C = A(MxK) * Bt(NxK)^T [+bias] ====
// 512 threads = 8 waves (2M x 4N). Per wave 128x64 output = 8x4 16x16 frags.
// LDS 128KB: A dbuf 2x32KB @0, B dbuf 2x32KB @64KB. Swizzle granule^=(row&7)
// on pre-swizzled global source + ds_read addr (0 bank conflicts, r2-verified).
// Phase = [stage][ds_reads][setprio1 MFMA setprio0][BARRIER] — no lgkm0, no
// pre-MFMA barrier: compiler's per-MFMA lgkmcnt(N) overlaps reads with MFMA.
template <int OUT_BF16, int ADD_BIAS>
__global__ __launch_bounds__(512, 2)
void gemm8(const bf16* __restrict__ A, int lda, const bf16* __restrict__ Bt,
           int ldb, void* __restrict__ Cout, int ldc,
           const float* __restrict__ bias, int K, int nbx) {
  __shared__ __align__(16) char smem[131072];
  const int tid = threadIdx.x;
  const int wid = tid >> 6, lane = tid & 63;
  const int lr = lane & 15, lk = lane >> 4;
  const int wm = wid >> 2, wn = wid & 3;
  const int nwg = gridDim.x, cpx = nwg >> 3;
  const int swz = ((int)blockIdx.x & 7) * cpx + ((int)blockIdx.x >> 3);
  const int bx = swz % nbx, by = swz / nbx;
  const int col0 = bx * 256, row0 = by * 256;

  char* sA = smem;
  char* sB = smem + 65536;

  const int srow = tid >> 3;
  const int sg = (tid & 7) ^ (srow & 7);
  const bf16* aStage = A + (long)(row0 + srow) * lda + sg * 8;
  const bf16* bStage = Bt + (long)(col0 + srow) * ldb + sg * 8;
  const int wOff = wid << 10;

  const int NT = K >> 6;

  const int sx = lr & 7;
  const int arow = wm * 128 + lr;
  const int brow = wn * 64 + lr;

  f32x4 acc[8][4];
  const f32x4 zero = {0.f, 0.f, 0.f, 0.f};
#pragma unroll
  for (int m = 0; m < 8; ++m)
#pragma unroll
    for (int n = 0; n < 4; ++n) acc[m][n] = zero;

  // ---- prologue: B(0), A(0) -> buf0; B(1) -> buf1.
#pragma unroll
  for (int h = 0; h < 2; ++h) {
    const bf16* g = bStage + (long)h * 128 * ldb;
    char* d = sB + h * 16384 + wOff;
    async_copy16(d, g);
    async_copy16(d + 8192, g + 64 * ldb);
  }
#pragma unroll
  for (int h = 0; h < 2; ++h) {
    const bf16* g = aStage + (long)h * 128 * lda;
    char* d = sA + h * 16384 + wOff;
    async_copy16(d, g);
    async_copy16(d + 8192, g + 64 * lda);
  }
#pragma unroll
  for (int h = 0; h < 2; ++h) {
    const bf16* g = bStage + (long)h * 128 * ldb + 64;
    char* d = sB + 32768 + h * 16384 + wOff;
    async_copy16(d, g);
    async_copy16(d + 8192, g + 64 * ldb);
  }
  VMCNT4();  // tile 0 landed (B(1)'s 4 issues may remain in flight)
  BARRIER();

  bf16x8 af[4][2], bl[2][2], bh[2][2];

  for (int t = 0; t < NT; ++t) {
    const int buf = t & 1;
    char* cA = sA + buf * 32768;
    char* cB = sB + buf * 32768;
    char* nA = sA + (buf ^ 1) * 32768;

    // ---------------- p0: stage A(t+1)h0; read afL+bl; MFMA Qll
    if (t + 1 < NT) {
      const bf16* g = aStage + (long)(t + 1) * 64;
      async_copy16(nA + wOff, g);
      async_copy16(nA + 8192 + wOff, g + 64 * lda);
    }
#pragma unroll
    for (int m = 0; m < 4; ++m)
#pragma unroll
      for (int kk = 0; kk < 2; ++kk)
        af[m][kk] = *(const bf16x8*)(cA + (arow + m * 16) * 128 +
                                     ((((kk << 2) | lk) ^ sx) << 4));
#pragma unroll
    for (int n = 0; n < 2; ++n)
#pragma unroll
      for (int kk = 0; kk < 2; ++kk)
        bl[n][kk] = *(const bf16x8*)(cB + (brow + n * 16) * 128 +
                                     ((((kk << 2) | lk) ^ sx) << 4));
    __builtin_amdgcn_s_setprio(1);
#pragma unroll
    for (int m = 0; m < 4; ++m)
#pragma unroll
      for (int n = 0; n < 2; ++n)
#pragma unroll
        for (int kk = 0; kk < 2; ++kk)
          acc[m][n] = __builtin_amdgcn_mfma_f32_16x16x32_bf16(
              af[m][kk], bl[n][kk], acc[m][n], 0, 0, 0);
    __builtin_amdgcn_s_setprio(0);
    BARRIER();

    // ---------------- p1: stage A(t+1)h1; read bh; MFMA Qlh
    if (t + 1 < NT) {
      const bf16* g = aStage + (long)128 * lda + (long)(t + 1) * 64;
      async_copy16(nA + 16384 + wOff, g);
      async_copy16(nA + 16384 + 8192 + wOff, g + 64 * lda);
    }
#pragma unroll
    for (int n = 0; n < 2; ++n)
#pragma unroll
      for (int kk = 0; kk < 2; ++kk)
        bh[n][kk] = *(const bf16x8*)(cB + (brow + (n + 2) * 16) * 128 +
                                     ((((kk << 2) | lk) ^ sx) << 4));
    __builtin_amdgcn_s_setprio(1);
#pragma unroll
    for (int m = 0; m < 4; ++m)
#pragma unroll
      for (int n = 0; n < 2; ++n)
#pragma unroll
        for (int kk = 0; kk < 2; ++kk)
          acc[m][n + 2] = __builtin_amdgcn_mfma_f32_16x16x32_bf16(
              af[m][kk], bh[n][kk], acc[m][n + 2], 0, 0, 0);
    __builtin_amdgcn_s_setprio(0);
    BARRIER();

    // ---------------- p2: stage B(t+2)h0 -> this buf; read afH; MFMA Qhl
    if (t + 2 < NT) {
      const bf16* g = bStage + (long)(t + 2) * 64;
      async_copy16(cB + wOff, g);
      async_copy16(cB + 8192 + wOff, g + 64 * ldb);
    }
#pragma unroll
    for (int m = 0; m < 4; ++m)
#pragma unroll
      for (int kk = 0; kk < 2; ++kk)
        af[m][kk] = *(const bf16x8*)(cA + (arow + (m + 4) * 16) * 128 +
                                     ((((kk << 2) | lk) ^ sx) << 4));
    __builtin_amdgcn_s_setprio(1);
#pragma unroll
    for (int m = 0; m < 4; ++m)
#pragma unroll
      for (int n = 0; n < 2; ++n)
#pragma unroll
        for (int kk = 0; kk < 2; ++kk)
          acc[m + 4][n] = __builtin_amdgcn_mfma_f32_16x16x32_bf16(
              af[m][kk], bl[n][kk], acc[m + 4][n], 0, 0, 0);
    __builtin_amdgcn_s_setprio(0);
    BARRIER();

    // ---------------- p3: stage B(t+2)h1; MFMA Qhh; counted vmcnt; barrier
    const int more = (t + 2 < NT);
    if (more) {
      const bf16* g = bStage + (long)128 * ldb + (long)(t + 2) * 64;
      async_copy16(cB + 16384 + wOff, g);
      async_copy16(cB + 16384 + 8192 + wOff, g + 64 * ldb);
    }
    __builtin_amdgcn_s_setprio(1);
#pragma unroll
    for (int m = 0; m < 4; ++m)
#pragma unroll
      for (int n = 0; n < 2; ++n)
#pragma unroll
        for (int kk = 0; kk < 2; ++kk)
          acc[m + 4][n + 2] = __builtin_amdgcn_mfma_f32_16x16x32_bf16(
              af[m][kk], bh[n][kk], acc[m + 4][n + 2], 0, 0, 0);
    __builtin_amdgcn_s_setprio(0);
    if (more) { VMCNT4(); } else { VMCNT0(); }
    BARRIER();
  }

  // ---- epilogue
#pragma unroll
  for (int m = 0; m < 8; ++m) {
#pragma unroll
    for (int n = 0; n < 4; ++n) {
      const int gc = col0 + wn * 64 + n * 16 + lr;
      const float bia = ADD_BIAS ? bias[gc] : 0.f;
#pragma unroll
      for (int j = 0; j < 4; ++j) {
        const int gr = row0 + wm * 128 + m * 16 + lk * 4 + j;
        const float v = acc[m][n][j] + bia;
        const long off = (long)gr * ldc + gc;
        if (OUT_BF16)
          ((bf16*)Cout)[off] = __float2bfloat16(v);
        else
          ((float*)Cout)[off] = v;
      }
    }
  }
}

// ---------------- transpose + fp32->bf16 convert ---------------------------
__global__ __launch_bounds__(256)
void tconv_kernel(const float* __restrict__ in, bf16* __restrict__ out,
                  int R, int C, int inBatch, int outBatch) {
  __shared__ float tile[32][33];
  const int tid = threadIdx.x;
  const int tx = tid & 31, ty = tid >> 5;
  const long ib = (long)blockIdx.z * inBatch;
  const long ob = (long)blockIdx.z * outBatch;
  const int c0 = blockIdx.x * 32, r0 = blockIdx.y * 32;
#pragma unroll
  for (int i = 0; i < 4; ++i)
    tile[ty + i * 8][tx] = in[ib + (long)(r0 + ty + i * 8) * C + c0 + tx];
  __syncthreads();
#pragma unroll
  for (int i = 0; i < 4; ++i)
    out[ob + (long)(c0 + ty + i * 8) * R + r0 + tx] =
        __float2bfloat16(tile[tx][ty + i * 8]);
}

// ---------------- prep: pair mean -> q, softmax scores, ps->bf16 ----------
__global__ __launch_bounds__(256)
void prep_kernel(const float* __restrict__ ps, const float* __restrict__ mac,
                 const float* __restrict__ pkeys, const float* __restrict__ mkeys,
                 bf16* __restrict__ psb, bf16* __restrict__ attn_p,
                 bf16* __restrict__ attn_m) {
  const int b = blockIdx.x, tid = threadIdx.x;
  __shared__ float q[PDIM];
  __shared__ float mrow[MDIM];
  const float* prow = ps + (long)b * DALL;
  if (tid < MDIM) mrow[tid] = mac[(long)b * MDIM + tid];
  if (tid < PDIM) {
    float s = 0.f;
#pragma unroll
    for (int p = 0; p < NPAIR; ++p) s += prow[p * PDIM + tid];
    q[tid] = s * (1.f / NPAIR);
  }
  for (int i = tid; i < DALL; i += 256)
    psb[(long)b * DALL + i] = __float2bfloat16(prow[i]);
  __syncthreads();
  const int wid = tid >> 6, lane = tid & 63;
  if (wid == 0) {
    float sc = 0.f;
    const float* kr = pkeys + lane * PDIM;
    for (int d = 0; d < PDIM; ++d) sc += q[d] * kr[d];
    sc *= 0.08838834764831845f;
    float mx = sc;
#pragma unroll
    for (int m = 32; m; m >>= 1) mx = fmaxf(mx, __shfl_xor(mx, m));
    float e = expf(sc - mx);
    float ssum = e;
#pragma unroll
    for (int m = 32; m; m >>= 1) ssum += __shfl_xor(ssum, m);
    attn_p[(long)b * NSLOT + lane] = __float2bfloat16(e / ssum);
  } else if (wid == 1) {
    float sc = 0.f;
    const float* kr = mkeys + lane * MDIM;
    for (int d = 0; d < MDIM; ++d) sc += mrow[d] * kr[d];
    sc *= 0.0625f;
    float mx = sc;
#pragma unroll
    for (int m = 32; m; m >>= 1) mx = fmaxf(mx, __shfl_xor(mx, m));
    float e = expf(sc - mx);
    float ssum = e;
#pragma unroll
    for (int m = 32; m; m >>= 1) ssum += __shfl_xor(ssum, m);
    attn_m[(long)b * NSLOT + lane] = __float2bfloat16(e / ssum);
  }
}

// ---------------- small-K bf16 GEMM (PV): 128x128, 2-barrier --------------
template <int OUT_BF16, int ADD_BIAS>
__global__ __launch_bounds__(256)
void gemm_bt(const bf16* __restrict__ A, int lda, const bf16* __restrict__ Bt,
             void* __restrict__ Cout, int ldc, int col_off,
             const float* __restrict__ bias, int K) {
  __shared__ __align__(16) bf16 sA[128 * 32];
  __shared__ __align__(16) bf16 sB[128 * 32];
  const int tid = threadIdx.x;
  const int wid = tid >> 6, lane = tid & 63;
  const int lr = lane & 15, lk = lane >> 4;
  const int col0 = blockIdx.x * 128, row0 = blockIdx.y * 128;
  const int wrow = (wid >> 1) * 64, wcol = (wid & 1) * 64;
  const int ea = tid * 8;
  const int ra = ea >> 5, ca = ea & 31;

  f32x4 acc[4][4];
  const f32x4 zero = {0.f, 0.f, 0.f, 0.f};
#pragma unroll
  for (int m = 0; m < 4; ++m)
#pragma unroll
    for (int n = 0; n < 4; ++n) acc[m][n] = zero;

  const long aBase = (long)row0 * lda;
  const long bBase = (long)col0 * K;
  char* sAb = (char*)sA;
  char* sBb = (char*)sB;
  const int wOff = wid * 1024;

  for (int kt = 0; kt < K; kt += 32) {
    __syncthreads();
#pragma unroll
    for (int i = 0; i < 2; ++i) {
      async_copy16(sAb + i * 4096 + wOff,
                   A + aBase + (long)(ra + i * 64) * lda + kt + ca);
      async_copy16(sBb + i * 4096 + wOff,
                   Bt + bBase + (long)(ra + i * 64) * K + kt + ca);
    }
    __syncthreads();
    bf16x8 af[4], bfr[4];
    const bf16x8* pA = (const bf16x8*)sA;
    const bf16x8* pB = (const bf16x8*)sB;
#pragma unroll
    for (int m = 0; m < 4; ++m) af[m] = pA[(wrow + m * 16 + lr) * 4 + lk];
#pragma unroll
    for (int n = 0; n < 4; ++n) bfr[n] = pB[(wcol + n * 16 + lr) * 4 + lk];
#pragma unroll
    for (int m = 0; m < 4; ++m)
#pragma unroll
      for (int n = 0; n < 4; ++n)
        acc[m][n] =
            __builtin_amdgcn_mfma_f32_16x16x32_bf16(af[m], bfr[n], acc[m][n], 0, 0, 0);
  }
#pragma unroll
  for (int m = 0; m < 4; ++m) {
#pragma unroll
    for (int n = 0; n < 4; ++n) {
      const int gcl = col0 + wcol + n * 16 + lr;
      const float bia = ADD_BIAS ? bias[gcl] : 0.f;
#pragma unroll
      for (int j = 0; j < 4; ++j) {
        const int gr = row0 + wrow + m * 16 + lk * 4 + j;
        const float v = acc[m][n][j] + bia;
        const long off = (long)gr * ldc + col_off + gcl;
        if (OUT_BF16)
          ((bf16*)Cout)[off] = __float2bfloat16(v);
        else
          ((float*)Cout)[off] = v;
      }
    }
  }
}

// ---------------- LayerNorm + exact GELU, bf16 in -> bf16 out -------------
__global__ __launch_bounds__(256)
void ln_gelu_kernel(const bf16* __restrict__ h, const float* __restrict__ g,
                    const float* __restrict__ bb, bf16* __restrict__ h2) {
  const int row = blockIdx.x, tid = threadIdx.x;
  const bf16* x = h + (long)row * DALL;
  float v[14];
  float s1 = 0.f, s2 = 0.f;
#pragma unroll
  for (int i = 0; i < 14; ++i) {
    v[i] = __bfloat162float(x[i * 256 + tid]);
    s1 += v[i];
    s2 += v[i] * v[i];
  }
#pragma unroll
  for (int m = 32; m; m >>= 1) {
    s1 += __shfl_xor(s1, m);
    s2 += __shfl_xor(s2, m);
  }
  __shared__ float r1[4], r2[4];
  const int wid = tid >> 6, lane = tid & 63;
  if (lane == 0) {
    r1[wid] = s1;
    r2[wid] = s2;
  }
  __syncthreads();
  s1 = r1[0] + r1[1] + r1[2] + r1[3];
  s2 = r2[0] + r2[1] + r2[2] + r2[3];
  const float mean = s1 * (1.f / DALL);
  const float var = s2 * (1.f / DALL) - mean * mean;
  const float rstd = rsqrtf(var + 1e-5f);
#pragma unroll
  for (int i = 0; i < 14; ++i) {
    const int c = i * 256 + tid;
    const float y = (v[i] - mean) * rstd * g[c] + bb[c];
    const float ge = 0.5f * y * (1.f + erff(y * 0.7071067811865475f));
    h2[(long)row * DALL + c] = __float2bfloat16(ge);
  }
}

// ---------------- per-pair GEMM (K=256) + LayerNorm epilogue --------------
__global__ __launch_bounds__(256)
void pair_final(const bf16* __restrict__ psb, const bf16* __restrict__ fusedb,
                const bf16* __restrict__ pwT, const float* __restrict__ pb,
                const float* __restrict__ lng, const float* __restrict__ lnb,
                float* __restrict__ out) {
  __shared__ __align__(16) bf16 sA[128 * 32];
  __shared__ __align__(16) bf16 sB[128 * 32];
  const int tid = threadIdx.x, wid = tid >> 6, lane = tid & 63;
  const int lr = lane & 15, lk = lane >> 4;
  const int p = blockIdx.y, row0 = blockIdx.x * 128;
  const int ea = tid * 8, ra = ea >> 5, ca = ea & 31;

  f32x4 acc[2][8];
  const f32x4 zero = {0.f, 0.f, 0.f, 0.f};
#pragma unroll
  for (int m = 0; m < 2; ++m)
#pragma unroll
    for (int n = 0; n < 8; ++n) acc[m][n] = zero;

  const bf16* pwp = pwT + (long)p * (PDIM * MDIM);
  char* sAb = (char*)sA;
  char* sBb = (char*)sB;
  const int wOff = wid * 1024;

  for (int kt = 0; kt < MDIM; kt += 32) {
    __syncthreads();
    const bf16* Asrc = (kt < PDIM) ? psb : fusedb;
    const int kc = kt & (PDIM - 1);
#pragma unroll
    for (int i = 0; i < 2; ++i) {
      async_copy16(sAb + i * 4096 + wOff,
                   Asrc + (long)(row0 + ra + i * 64) * DALL + p * PDIM + kc + ca);
      async_copy16(sBb + i * 4096 + wOff, pwp + (ra + i * 64) * MDIM + kt + ca);
    }
    __syncthreads();
    bf16x8 af[2], bfr[8];
    const bf16x8* pA = (const bf16x8*)sA;
    const bf16x8* pB = (const bf16x8*)sB;
#pragma unroll
    for (int m = 0; m < 2; ++m) af[m] = pA[(wid * 32 + m * 16 + lr) * 4 + lk];
#pragma unroll
    for (int n = 0; n < 8; ++n) bfr[n] = pB[(n * 16 + lr) * 4 + lk];
#pragma unroll
    for (int m = 0; m < 2; ++m)
#pragma unroll
      for (int n = 0; n < 8; ++n)
        acc[m][n] =
            __builtin_amdgcn_mfma_f32_16x16x32_bf16(af[m], bfr[n], acc[m][n], 0, 0, 0);
  }
  float g_[8], b_[8], pb_[8];
#pragma unroll
  for (int n = 0; n < 8; ++n) {
    const int c = n * 16 + lr;
    g_[n] = lng[p * PDIM + c];
    b_[n] = lnb[p * PDIM + c];
    pb_[n] = pb[p * PDIM + c];
  }
#pragma unroll
  for (int m = 0; m < 2; ++m) {
#pragma unroll
    for (int j = 0; j < 4; ++j) {
      float vv[8];
      float s1 = 0.f, s2 = 0.f;
#pragma unroll
      for (int n = 0; n < 8; ++n) {
        vv[n] = acc[m][n][j] + pb_[n];
        s1 += vv[n];
        s2 += vv[n] * vv[n];
      }
#pragma unroll
      for (int msk = 1; msk <= 8; msk <<= 1) {
        s1 += __shfl_xor(s1, msk);
        s2 += __shfl_xor(s2, msk);
      }
      const float mean = s1 * (1.f / 128.f);
      const float var = s2 * (1.f / 128.f) - mean * mean;
      const float rstd = rsqrtf(var + 1e-5f);
      const int gr = row0 + wid * 32 + m * 16 + lk * 4 + j;
      float* orow = out + ((long)gr * NPAIR + p) * PDIM;
#pragma unroll
      for (int n = 0; n < 8; ++n)
        orow[n * 16 + lr] = (vv[n] - mean) * rstd * g_[n] + b_[n];
    }
  }
}

// ---------------------------------------------------------------------------
extern "C" void kernel_launch(void* const* d_in, const int* in_sizes, int n_in,
                              void* d_out, int out_size, void* d_ws, size_t ws_size,
                              hipStream_t stream) {
  (void)in_sizes; (void)n_in; (void)out_size; (void)ws_size;
  const float* ps   = (const float*)d_in[0];
  const float* mac  = (const float*)d_in[1];
  const float* pkey = (const float*)d_in[2];
  const float* pval = (const float*)d_in[3];
  const float* mkey = (const float*)d_in[4];
  const float* mval = (const float*)d_in[5];
  const float* w1   = (const float*)d_in[6];
  const float* b1   = (const float*)d_in[7];
  const float* lng1 = (const float*)d_in[8];
  const float* lnb1 = (const float*)d_in[9];
  const float* w2   = (const float*)d_in[10];
  const float* b2   = (const float*)d_in[11];
  const float* pw   = (const float*)d_in[12];
  const float* pb   = (const float*)d_in[13];
  const float* plng = (const float*)d_in[14];
  const float* plnb = (const float*)d_in[15];
  float* out = (float*)d_out;

  char* w = (char*)d_ws;
  size_t off = 0;
  auto carve = [&](size_t bytes) {
    char* pp = w + off;
    off += (bytes + 255) & ~(size_t)255;
    return pp;
  };
  bf16* psb   = (bf16*)carve((size_t)B_SZ * DALL * 2);
  bf16* w1t   = (bf16*)carve((size_t)DALL * DCAT * 2);
  bf16* w2t   = (bf16*)carve((size_t)DALL * DALL * 2);
  bf16* pvT   = (bf16*)carve((size_t)DALL * NSLOT * 2);
  bf16* mvT   = (bf16*)carve((size_t)DALL * NSLOT * 2);
  bf16* pwTb  = (bf16*)carve((size_t)NPAIR * PDIM * MDIM * 2);
  bf16* atp   = (bf16*)carve((size_t)B_SZ * NSLOT * 2);
  bf16* atm   = (bf16*)carve((size_t)B_SZ * NSLOT * 2);
  bf16* hin   = (bf16*)carve((size_t)B_SZ * DCAT * 2);
  bf16* hpreb = (bf16*)carve((size_t)B_SZ * DALL * 2);  // GEMM1 out (bf16)
  bf16* h2     = w1t;    // alias: written after GEMM1 consumed w1t
  bf16* fusedb = hpreb;  // alias: written after ln_gelu consumed hpreb

  tconv_kernel<<<dim3(DALL / 32, DCAT / 32, 1), 256, 0, stream>>>(w1, w1t, DCAT, DALL, 0, 0);
  tconv_kernel<<<dim3(DALL / 32, DALL / 32, 1), 256, 0, stream>>>(w2, w2t, DALL, DALL, 0, 0);
  tconv_kernel<<<dim3(DALL / 32, NSLOT / 32, 1), 256, 0, stream>>>(pval, pvT, NSLOT, DALL, 0, 0);
  tconv_kernel<<<dim3(DALL / 32, NSLOT / 32, 1), 256, 0, stream>>>(mval, mvT, NSLOT, DALL, 0, 0);
  tconv_kernel<<<dim3(PDIM / 32, MDIM / 32, NPAIR), 256, 0, stream>>>(
      pw, pwTb, MDIM, PDIM, MDIM * PDIM, MDIM * PDIM);
  prep_kernel<<<dim3(B_SZ), 256, 0, stream>>>(ps, mac, pkey, mkey, psb, atp, atm);
  gemm_bt<1, 0><<<dim3(DALL / 128, B_SZ / 128), 256, 0, stream>>>(
      atp, NSLOT, pvT, hin, DCAT, 0, nullptr, NSLOT);
  gemm_bt<1, 0><<<dim3(DALL / 128, B_SZ / 128), 256, 0, stream>>>(
      atm, NSLOT, mvT, hin, DCAT, DALL, nullptr, NSLOT);
  // GEMM1: (4096 x 7168) @ (7168 x 3584)^T -> bf16 hpreb
  gemm8<1, 1><<<dim3((DALL / 256) * (B_SZ / 256)), 512, 0, stream>>>(
      hin, DCAT, w1t, DCAT, hpreb, DALL, b1, DCAT, DALL / 256);
  ln_gelu_kernel<<<dim3(B_SZ), 256, 0, stream>>>(hpreb, lng1, lnb1, h2);
  // GEMM2: (4096 x 3584) @ (3584 x 3584)^T -> bf16 fused
  gemm8<1, 1><<<dim3((DALL / 256) * (B_SZ / 256)), 512, 0, stream>>>(
      h2, DALL, w2t, DALL, fusedb, DALL, b2, DALL, DALL / 256);
  pair_final<<<dim3(B_SZ / 128, NPAIR), 256, 0, stream>>>(
      psb, fusedb, pwTb, pb, plng, plnb, out);
}

// Round 4
// 310.637 us; speedup vs baseline: 2.3412x; 1.5281x over previous
//
#include <hip/hip_runtime.h>
#include <hip/hip_bf16.h>
#include <math.h>

// CrossPairMemory round 4: algebraic restructure. GEMM1 is rank-128:
//   h = attn_p @ (pair_vals @ W1_top) + attn_m @ (macro_vals @ W1_bot) + b1
// -> precompute CVt (3584x128, K-split MFMA) + thin K=128 GEMM. The two PV
// GEMMs and the 58MB hin buffer disappear. GEMM2 stays on gemm8 (r3).

#define B_SZ  4096
#define NPAIR 28
#define PDIM  128
#define MDIM  256
#define NSLOT 64
#define DALL  3584
#define DCAT  7168
#define KSPLIT 8
#define KCHUNK 448   // DALL / KSPLIT

typedef __hip_bfloat16 bf16;
typedef __attribute__((ext_vector_type(8))) short bf16x8;
typedef __attribute__((ext_vector_type(4))) float f32x4;

#define BARRIER() asm volatile("s_barrier" ::: "memory")
#define VMCNT4()  asm volatile("s_waitcnt vmcnt(4)" ::: "memory")
#define VMCNT0()  asm volatile("s_waitcnt vmcnt(0)" ::: "memory")

__device__ __forceinline__ void async_copy16(void* lds, const void* g) {
  __builtin_amdgcn_global_load_lds((__attribute__((address_space(1))) void*)g,
                                   (__attribute__((address_space(3))) void*)lds,
                                   16, 0, 0);
}

// ============== 256x256x64 4-phase GEMM (r3, verified) =====================
template <int OUT_BF16, int ADD_BIAS>
__global__ __launch_bounds__(512, 2)
void gemm8(const bf16* __restrict__ A, int lda, const bf16* __restrict__ Bt,
           int ldb, void* __restrict__ Cout, int ldc,
           const float* __restrict__ bias, int K, int nbx) {
  __shared__ __align__(16) char smem[131072];
  const int tid = threadIdx.x;
  const int wid = tid >> 6, lane = tid & 63;
  const int lr = lane & 15, lk = lane >> 4;
  const int wm = wid >> 2, wn = wid & 3;
  const int nwg = gridDim.x, cpx = nwg >> 3;
  const int swz = ((int)blockIdx.x & 7) * cpx + ((int)blockIdx.x >> 3);
  const int bx = swz % nbx, by = swz / nbx;
  const int col0 = bx * 256, row0 = by * 256;

  char* sA = smem;
  char* sB = smem + 65536;

  const int srow = tid >> 3;
  const int sg = (tid & 7) ^ (srow & 7);
  const bf16* aStage = A + (long)(row0 + srow) * lda + sg * 8;
  const bf16* bStage = Bt + (long)(col0 + srow) * ldb + sg * 8;
  const int wOff = wid << 10;

  const int NT = K >> 6;

  const int sx = lr & 7;
  const int arow = wm * 128 + lr;
  const int brow = wn * 64 + lr;

  f32x4 acc[8][4];
  const f32x4 zero = {0.f, 0.f, 0.f, 0.f};
#pragma unroll
  for (int m = 0; m < 8; ++m)
#pragma unroll
    for (int n = 0; n < 4; ++n) acc[m][n] = zero;

#pragma unroll
  for (int h = 0; h < 2; ++h) {
    const bf16* g = bStage + (long)h * 128 * ldb;
    char* d = sB + h * 16384 + wOff;
    async_copy16(d, g);
    async_copy16(d + 8192, g + 64 * ldb);
  }
#pragma unroll
  for (int h = 0; h < 2; ++h) {
    const bf16* g = aStage + (long)h * 128 * lda;
    char* d = sA + h * 16384 + wOff;
    async_copy16(d, g);
    async_copy16(d + 8192, g + 64 * lda);
  }
#pragma unroll
  for (int h = 0; h < 2; ++h) {
    const bf16* g = bStage + (long)h * 128 * ldb + 64;
    char* d = sB + 32768 + h * 16384 + wOff;
    async_copy16(d, g);
    async_copy16(d + 8192, g + 64 * ldb);
  }
  VMCNT4();
  BARRIER();

  bf16x8 af[4][2], bl[2][2], bh[2][2];

  for (int t = 0; t < NT; ++t) {
    const int buf = t & 1;
    char* cA = sA + buf * 32768;
    char* cB = sB + buf * 32768;
    char* nA = sA + (buf ^ 1) * 32768;

    if (t + 1 < NT) {
      const bf16* g = aStage + (long)(t + 1) * 64;
      async_copy16(nA + wOff, g);
      async_copy16(nA + 8192 + wOff, g + 64 * lda);
    }
#pragma unroll
    for (int m = 0; m < 4; ++m)
#pragma unroll
      for (int kk = 0; kk < 2; ++kk)
        af[m][kk] = *(const bf16x8*)(cA + (arow + m * 16) * 128 +
                                     ((((kk << 2) | lk) ^ sx) << 4));
#pragma unroll
    for (int n = 0; n < 2; ++n)
#pragma unroll
      for (int kk = 0; kk < 2; ++kk)
        bl[n][kk] = *(const bf16x8*)(cB + (brow + n * 16) * 128 +
                                     ((((kk << 2) | lk) ^ sx) << 4));
    __builtin_amdgcn_s_setprio(1);
#pragma unroll
    for (int m = 0; m < 4; ++m)
#pragma unroll
      for (int n = 0; n < 2; ++n)
#pragma unroll
        for (int kk = 0; kk < 2; ++kk)
          acc[m][n] = __builtin_amdgcn_mfma_f32_16x16x32_bf16(
              af[m][kk], bl[n][kk], acc[m][n], 0, 0, 0);
    __builtin_amdgcn_s_setprio(0);
    BARRIER();

    if (t + 1 < NT) {
      const bf16* g = aStage + (long)128 * lda + (long)(t + 1) * 64;
      async_copy16(nA + 16384 + wOff, g);
      async_copy16(nA + 16384 + 8192 + wOff, g + 64 * lda);
    }
#pragma unroll
    for (int n = 0; n < 2; ++n)
#pragma unroll
      for (int kk = 0; kk < 2; ++kk)
        bh[n][kk] = *(const bf16x8*)(cB + (brow + (n + 2) * 16) * 128 +
                                     ((((kk << 2) | lk) ^ sx) << 4));
    __builtin_amdgcn_s_setprio(1);
#pragma unroll
    for (int m = 0; m < 4; ++m)
#pragma unroll
      for (int n = 0; n < 2; ++n)
#pragma unroll
        for (int kk = 0; kk < 2; ++kk)
          acc[m][n + 2] = __builtin_amdgcn_mfma_f32_16x16x32_bf16(
              af[m][kk], bh[n][kk], acc[m][n + 2], 0, 0, 0);
    __builtin_amdgcn_s_setprio(0);
    BARRIER();

    if (t + 2 < NT) {
      const bf16* g = bStage + (long)(t + 2) * 64;
      async_copy16(cB + wOff, g);
      async_copy16(cB + 8192 + wOff, g + 64 * ldb);
    }
#pragma unroll
    for (int m = 0; m < 4; ++m)
#pragma unroll
      for (int kk = 0; kk < 2; ++kk)
        af[m][kk] = *(const bf16x8*)(cA + (arow + (m + 4) * 16) * 128 +
                                     ((((kk << 2) | lk) ^ sx) << 4));
    __builtin_amdgcn_s_setprio(1);
#pragma unroll
    for (int m = 0; m < 4; ++m)
#pragma unroll
      for (int n = 0; n < 2; ++n)
#pragma unroll
        for (int kk = 0; kk < 2; ++kk)
          acc[m + 4][n] = __builtin_amdgcn_mfma_f32_16x16x32_bf16(
              af[m][kk], bl[n][kk], acc[m + 4][n], 0, 0, 0);
    __builtin_amdgcn_s_setprio(0);
    BARRIER();

    const int more = (t + 2 < NT);
    if (more) {
      const bf16* g = bStage + (long)128 * ldb + (long)(t + 2) * 64;
      async_copy16(cB + 16384 + wOff, g);
      async_copy16(cB + 16384 + 8192 + wOff, g + 64 * ldb);
    }
    __builtin_amdgcn_s_setprio(1);
#pragma unroll
    for (int m = 0; m < 4; ++m)
#pragma unroll
      for (int n = 0; n < 2; ++n)
#pragma unroll
        for (int kk = 0; kk < 2; ++kk)
          acc[m + 4][n + 2] = __builtin_amdgcn_mfma_f32_16x16x32_bf16(
              af[m][kk], bh[n][kk], acc[m + 4][n + 2], 0, 0, 0);
    __builtin_amdgcn_s_setprio(0);
    if (more) { VMCNT4(); } else { VMCNT0(); }
    BARRIER();
  }

#pragma unroll
  for (int m = 0; m < 8; ++m) {
#pragma unroll
    for (int n = 0; n < 4; ++n) {
      const int gc = col0 + wn * 64 + n * 16 + lr;
      const float bia = ADD_BIAS ? bias[gc] : 0.f;
#pragma unroll
      for (int j = 0; j < 4; ++j) {
        const int gr = row0 + wm * 128 + m * 16 + lk * 4 + j;
        const float v = acc[m][n][j] + bia;
        const long off = (long)gr * ldc + gc;
        if (OUT_BF16)
          ((bf16*)Cout)[off] = __float2bfloat16(v);
        else
          ((float*)Cout)[off] = v;
      }
    }
  }
}

// ---------------- transpose + fp32->bf16 convert ---------------------------
__global__ __launch_bounds__(256)
void tconv_kernel(const float* __restrict__ in, bf16* __restrict__ out,
                  int R, int C, int inBatch, int outBatch) {
  __shared__ float tile[32][33];
  const int tid = threadIdx.x;
  const int tx = tid & 31, ty = tid >> 5;
  const long ib = (long)blockIdx.z * inBatch;
  const long ob = (long)blockIdx.z * outBatch;
  const int c0 = blockIdx.x * 32, r0 = blockIdx.y * 32;
#pragma unroll
  for (int i = 0; i < 4; ++i)
    tile[ty + i * 8][tx] = in[ib + (long)(r0 + ty + i * 8) * C + c0 + tx];
  __syncthreads();
#pragma unroll
  for (int i = 0; i < 4; ++i)
    out[ob + (long)(c0 + ty + i * 8) * R + r0 + tx] =
        __float2bfloat16(tile[tx][ty + i * 8]);
}

// ---------------- plain fp32->bf16 convert ---------------------------------
__global__ __launch_bounds__(256)
void conv_kernel(const float* __restrict__ in, bf16* __restrict__ out, int n) {
  const int i = (blockIdx.x * 256 + threadIdx.x) * 8;
  if (i + 7 < n) {
    float4 a = *(const float4*)(in + i);
    float4 b = *(const float4*)(in + i + 4);
    bf16 o[8];
    o[0] = __float2bfloat16(a.x); o[1] = __float2bfloat16(a.y);
    o[2] = __float2bfloat16(a.z); o[3] = __float2bfloat16(a.w);
    o[4] = __float2bfloat16(b.x); o[5] = __float2bfloat16(b.y);
    o[6] = __float2bfloat16(b.z); o[7] = __float2bfloat16(b.w);
    *(bf16x8*)(out + i) = *(bf16x8*)o;
  }
}

// ---------------- prep: pair mean -> q, softmax scores, ps->bf16 ----------
__global__ __launch_bounds__(256)
void prep_kernel(const float* __restrict__ ps, const float* __restrict__ mac,
                 const float* __restrict__ pkeys, const float* __restrict__ mkeys,
                 bf16* __restrict__ psb, bf16* __restrict__ att) {
  const int b = blockIdx.x, tid = threadIdx.x;
  __shared__ float q[PDIM];
  __shared__ float mrow[MDIM];
  const float* prow = ps + (long)b * DALL;
  if (tid < MDIM) mrow[tid] = mac[(long)b * MDIM + tid];
  if (tid < PDIM) {
    float s = 0.f;
#pragma unroll
    for (int p = 0; p < NPAIR; ++p) s += prow[p * PDIM + tid];
    q[tid] = s * (1.f / NPAIR);
  }
  for (int i = tid; i < DALL; i += 256)
    psb[(long)b * DALL + i] = __float2bfloat16(prow[i]);
  __syncthreads();
  const int wid = tid >> 6, lane = tid & 63;
  if (wid == 0) {
    float sc = 0.f;
    const float* kr = pkeys + lane * PDIM;
    for (int d = 0; d < PDIM; ++d) sc += q[d] * kr[d];
    sc *= 0.08838834764831845f;
    float mx = sc;
#pragma unroll
    for (int m = 32; m; m >>= 1) mx = fmaxf(mx, __shfl_xor(mx, m));
    float e = expf(sc - mx);
    float ssum = e;
#pragma unroll
    for (int m = 32; m; m >>= 1) ssum += __shfl_xor(ssum, m);
    att[(long)b * 128 + lane] = __float2bfloat16(e / ssum);
  } else if (wid == 1) {
    float sc = 0.f;
    const float* kr = mkeys + lane * MDIM;
    for (int d = 0; d < MDIM; ++d) sc += mrow[d] * kr[d];
    sc *= 0.0625f;
    float mx = sc;
#pragma unroll
    for (int m = 32; m; m >>= 1) mx = fmaxf(mx, __shfl_xor(mx, m));
    float e = expf(sc - mx);
    float ssum = e;
#pragma unroll
    for (int m = 32; m; m >>= 1) ssum += __shfl_xor(ssum, m);
    att[(long)b * 128 + 64 + lane] = __float2bfloat16(e / ssum);
  }
}

// ---------------- CVt precompute: part[ks][n][128] += w1t-half @ vals ------
// CVt[n][s]      = sum_k w1t[n][k]        * pair_vals[s][k]   (s in 0..63)
// CVt[n][64+s]   = sum_k w1t[n][DALL+k]   * macro_vals[s][k]
// grid (14 n-blocks, 2 halves, KSPLIT). Tile 256(n) x 64(s) x BK=32; 4 waves
// stacked in n, each 64x64 via 4x4 16x16x32 MFMA. fp32 partials to ws.
__global__ __launch_bounds__(256)
void precompute_cvt(const bf16* __restrict__ w1t, const bf16* __restrict__ pvb,
                    const bf16* __restrict__ mvb, float* __restrict__ part) {
  __shared__ __align__(16) bf16 sA[256 * 32];
  __shared__ __align__(16) bf16 sB[64 * 32];
  const int tid = threadIdx.x, wid = tid >> 6, lane = tid & 63;
  const int lr = lane & 15, lk = lane >> 4;
  const int n0 = blockIdx.x * 256;
  const int half = blockIdx.y;
  const int ks = blockIdx.z;
  const bf16* A = w1t + (long)half * DALL;     // A[n][k] at n*DCAT + k
  const bf16* Bt = half ? mvb : pvb;           // [64][DALL]
  const int kbase = ks * KCHUNK;

  f32x4 acc[4][4];
  const f32x4 zero = {0.f, 0.f, 0.f, 0.f};
#pragma unroll
  for (int m = 0; m < 4; ++m)
#pragma unroll
    for (int n = 0; n < 4; ++n) acc[m][n] = zero;

  for (int kt = 0; kt < KCHUNK; kt += 32) {
    __syncthreads();
#pragma unroll
    for (int i = 0; i < 4; ++i) {
      const int g = tid + i * 256, r = g >> 2, c8 = g & 3;
      async_copy16((char*)sA + g * 16,
                   A + (long)(n0 + r) * DCAT + kbase + kt + c8 * 8);
    }
    {
      const int g = tid, r = g >> 2, c8 = g & 3;
      async_copy16((char*)sB + g * 16, Bt + (long)r * DALL + kbase + kt + c8 * 8);
    }
    __syncthreads();
    bf16x8 af[4], bfr[4];
    const bf16x8* pA = (const bf16x8*)sA;
    const bf16x8* pB = (const bf16x8*)sB;
#pragma unroll
    for (int m = 0; m < 4; ++m) af[m] = pA[(wid * 64 + m * 16 + lr) * 4 + lk];
#pragma unroll
    for (int n = 0; n < 4; ++n) bfr[n] = pB[(n * 16 + lr) * 4 + lk];
#pragma unroll
    for (int m = 0; m < 4; ++m)
#pragma unroll
      for (int n = 0; n < 4; ++n)
        acc[m][n] =
            __builtin_amdgcn_mfma_f32_16x16x32_bf16(af[m], bfr[n], acc[m][n], 0, 0, 0);
  }
#pragma unroll
  for (int m = 0; m < 4; ++m)
#pragma unroll
    for (int n = 0; n < 4; ++n)
#pragma unroll
      for (int j = 0; j < 4; ++j) {
        const int gn = n0 + wid * 64 + m * 16 + lk * 4 + j;
        const int s = n * 16 + lr;
        part[((long)ks * DALL + gn) * 128 + half * 64 + s] = acc[m][n][j];
      }
}

// ---------------- reduce K-split partials -> CVt bf16 [3584][128] ---------
__global__ __launch_bounds__(256)
void reduce_cvt(const float* __restrict__ part, bf16* __restrict__ cvt) {
  const long i = ((long)blockIdx.x * 256 + threadIdx.x) * 4;
  f32x4 s = {0.f, 0.f, 0.f, 0.f};
#pragma unroll
  for (int ks = 0; ks < KSPLIT; ++ks)
    s += *(const f32x4*)(part + (long)ks * DALL * 128 + i);
#pragma unroll
  for (int k = 0; k < 4; ++k) cvt[i + k] = __float2bfloat16(s[k]);
}

// ---------------- 128x128 2-barrier GEMM (thin K) --------------------------
template <int OUT_BF16, int ADD_BIAS>
__global__ __launch_bounds__(256)
void gemm_bt(const bf16* __restrict__ A, int lda, const bf16* __restrict__ Bt,
             void* __restrict__ Cout, int ldc, int col_off,
             const float* __restrict__ bias, int K) {
  __shared__ __align__(16) bf16 sA[128 * 32];
  __shared__ __align__(16) bf16 sB[128 * 32];
  const int tid = threadIdx.x;
  const int wid = tid >> 6, lane = tid & 63;
  const int lr = lane & 15, lk = lane >> 4;
  const int col0 = blockIdx.x * 128, row0 = blockIdx.y * 128;
  const int wrow = (wid >> 1) * 64, wcol = (wid & 1) * 64;
  const int ea = tid * 8;
  const int ra = ea >> 5, ca = ea & 31;

  f32x4 acc[4][4];
  const f32x4 zero = {0.f, 0.f, 0.f, 0.f};
#pragma unroll
  for (int m = 0; m < 4; ++m)
#pragma unroll
    for (int n = 0; n < 4; ++n) acc[m][n] = zero;

  const long aBase = (long)row0 * lda;
  const long bBase = (long)col0 * K;
  char* sAb = (char*)sA;
  char* sBb = (char*)sB;
  const int wOff = wid * 1024;

  for (int kt = 0; kt < K; kt += 32) {
    __syncthreads();
#pragma unroll
    for (int i = 0; i < 2; ++i) {
      async_copy16(sAb + i * 4096 + wOff,
                   A + aBase + (long)(ra + i * 64) * lda + kt + ca);
      async_copy16(sBb + i * 4096 + wOff,
                   Bt + bBase + (long)(ra + i * 64) * K + kt + ca);
    }
    __syncthreads();
    bf16x8 af[4], bfr[4];
    const bf16x8* pA = (const bf16x8*)sA;
    const bf16x8* pB = (const bf16x8*)sB;
#pragma unroll
    for (int m = 0; m < 4; ++m) af[m] = pA[(wrow + m * 16 + lr) * 4 + lk];
#pragma unroll
    for (int n = 0; n < 4; ++n) bfr[n] = pB[(wcol + n * 16 + lr) * 4 + lk];
#pragma unroll
    for (int m = 0; m < 4; ++m)
#pragma unroll
      for (int n = 0; n < 4; ++n)
        acc[m][n] =
            __builtin_amdgcn_mfma_f32_16x16x32_bf16(af[m], bfr[n], acc[m][n], 0, 0, 0);
  }
#pragma unroll
  for (int m = 0; m < 4; ++m) {
#pragma unroll
    for (int n = 0; n < 4; ++n) {
      const int gcl = col0 + wcol + n * 16 + lr;
      const float bia = ADD_BIAS ? bias[gcl] : 0.f;
#pragma unroll
      for (int j = 0; j < 4; ++j) {
        const int gr = row0 + wrow + m * 16 + lk * 4 + j;
        const float v = acc[m][n][j] + bia;
        const long off = (long)gr * ldc + col_off + gcl;
        if (OUT_BF16)
          ((bf16*)Cout)[off] = __float2bfloat16(v);
        else
          ((float*)Cout)[off] = v;
      }
    }
  }
}

// ---------------- LayerNorm + exact GELU, bf16 in -> bf16 out -------------
__global__ __launch_bounds__(256)
void ln_gelu_kernel(const bf16* __restrict__ h, const float* __restrict__ g,
                    const float* __restrict__ bb, bf16* __restrict__ h2) {
  const int row = blockIdx.x, tid = threadIdx.x;
  const bf16* x = h + (long)row * DALL;
  float v[14];
  float s1 = 0.f, s2 = 0.f;
#pragma unroll
  for (int i = 0; i < 14; ++i) {
    v[i] = __bfloat162float(x[i * 256 + tid]);
    s1 += v[i];
    s2 += v[i] * v[i];
  }
#pragma unroll
  for (int m = 32; m; m >>= 1) {
    s1 += __shfl_xor(s1, m);
    s2 += __shfl_xor(s2, m);
  }
  __shared__ float r1[4], r2[4];
  const int wid = tid >> 6, lane = tid & 63;
  if (lane == 0) {
    r1[wid] = s1;
    r2[wid] = s2;
  }
  __syncthreads();
  s1 = r1[0] + r1[1] + r1[2] + r1[3];
  s2 = r2[0] + r2[1] + r2[2] + r2[3];
  const float mean = s1 * (1.f / DALL);
  const float var = s2 * (1.f / DALL) - mean * mean;
  const float rstd = rsqrtf(var + 1e-5f);
#pragma unroll
  for (int i = 0; i < 14; ++i) {
    const int c = i * 256 + tid;
    const float y = (v[i] - mean) * rstd * g[c] + bb[c];
    const float ge = 0.5f * y * (1.f + erff(y * 0.7071067811865475f));
    h2[(long)row * DALL + c] = __float2bfloat16(ge);
  }
}

// ---------------- per-pair GEMM (K=256) + LayerNorm epilogue --------------
__global__ __launch_bounds__(256)
void pair_final(const bf16* __restrict__ psb, const bf16* __restrict__ fusedb,
                const bf16* __restrict__ pwT, const float* __restrict__ pb,
                const float* __restrict__ lng, const float* __restrict__ lnb,
                float* __restrict__ out) {
  __shared__ __align__(16) bf16 sA[128 * 32];
  __shared__ __align__(16) bf16 sB[128 * 32];
  const int tid = threadIdx.x, wid = tid >> 6, lane = tid & 63;
  const int lr = lane & 15, lk = lane >> 4;
  const int p = blockIdx.y, row0 = blockIdx.x * 128;
  const int ea = tid * 8, ra = ea >> 5, ca = ea & 31;

  f32x4 acc[2][8];
  const f32x4 zero = {0.f, 0.f, 0.f, 0.f};
#pragma unroll
  for (int m = 0; m < 2; ++m)
#pragma unroll
    for (int n = 0; n < 8; ++n) acc[m][n] = zero;

  const bf16* pwp = pwT + (long)p * (PDIM * MDIM);
  char* sAb = (char*)sA;
  char* sBb = (char*)sB;
  const int wOff = wid * 1024;

  for (int kt = 0; kt < MDIM; kt += 32) {
    __syncthreads();
    const bf16* Asrc = (kt < PDIM) ? psb : fusedb;
    const int kc = kt & (PDIM - 1);
#pragma unroll
    for (int i = 0; i < 2; ++i) {
      async_copy16(sAb + i * 4096 + wOff,
                   Asrc + (long)(row0 + ra + i * 64) * DALL + p * PDIM + kc + ca);
      async_copy16(sBb + i * 4096 + wOff, pwp + (ra + i * 64) * MDIM + kt + ca);
    }
    __syncthreads();
    bf16x8 af[2], bfr[8];
    const bf16x8* pA = (const bf16x8*)sA;
    const bf16x8* pB = (const bf16x8*)sB;
#pragma unroll
    for (int m = 0; m < 2; ++m) af[m] = pA[(wid * 32 + m * 16 + lr) * 4 + lk];
#pragma unroll
    for (int n = 0; n < 8; ++n) bfr[n] = pB[(n * 16 + lr) * 4 + lk];
#pragma unroll
    for (int m = 0; m < 2; ++m)
#pragma unroll
      for (int n = 0; n < 8; ++n)
        acc[m][n] =
            __builtin_amdgcn_mfma_f32_16x16x32_bf16(af[m], bfr[n], acc[m][n], 0, 0, 0);
  }
  float g_[8], b_[8], pb_[8];
#pragma unroll
  for (int n = 0; n < 8; ++n) {
    const int c = n * 16 + lr;
    g_[n] = lng[p * PDIM + c];
    b_[n] = lnb[p * PDIM + c];
    pb_[n] = pb[p * PDIM + c];
  }
#pragma unroll
  for (int m = 0; m < 2; ++m) {
#pragma unroll
    for (int j = 0; j < 4; ++j) {
      float vv[8];
      float s1 = 0.f, s2 = 0.f;
#pragma unroll
      for (int n = 0; n < 8; ++n) {
        vv[n] = acc[m][n][j] + pb_[n];
        s1 += vv[n];
        s2 += vv[n] * vv[n];
      }
#pragma unroll
      for (int msk = 1; msk <= 8; msk <<= 1) {
        s1 += __shfl_xor(s1, msk);
        s2 += __shfl_xor(s2, msk);
      }
      const float mean = s1 * (1.f / 128.f);
      const float var = s2 * (1.f / 128.f) - mean * mean;
      const float rstd = rsqrtf(var + 1e-5f);
      const int gr = row0 + wid * 32 + m * 16 + lk * 4 + j;
      float* orow = out + ((long)gr * NPAIR + p) * PDIM;
#pragma unroll
      for (int n = 0; n < 8; ++n)
        orow[n * 16 + lr] = (vv[n] - mean) * rstd * g_[n] + b_[n];
    }
  }
}

// ---------------------------------------------------------------------------
extern "C" void kernel_launch(void* const* d_in, const int* in_sizes, int n_in,
                              void* d_out, int out_size, void* d_ws, size_t ws_size,
                              hipStream_t stream) {
  (void)in_sizes; (void)n_in; (void)out_size; (void)ws_size;
  const float* ps   = (const float*)d_in[0];
  const float* mac  = (const float*)d_in[1];
  const float* pkey = (const float*)d_in[2];
  const float* pval = (const float*)d_in[3];
  const float* mkey = (const float*)d_in[4];
  const float* mval = (const float*)d_in[5];
  const float* w1   = (const float*)d_in[6];
  const float* b1   = (const float*)d_in[7];
  const float* lng1 = (const float*)d_in[8];
  const float* lnb1 = (const float*)d_in[9];
  const float* w2   = (const float*)d_in[10];
  const float* b2   = (const float*)d_in[11];
  const float* pw   = (const float*)d_in[12];
  const float* pb   = (const float*)d_in[13];
  const float* plng = (const float*)d_in[14];
  const float* plnb = (const float*)d_in[15];
  float* out = (float*)d_out;

  char* w = (char*)d_ws;
  size_t off = 0;
  auto carve = [&](size_t bytes) {
    char* pp = w + off;
    off += (bytes + 255) & ~(size_t)255;
    return pp;
  };
  bf16* psb   = (bf16*)carve((size_t)B_SZ * DALL * 2);          // 29.4 MB
  bf16* w1t   = (bf16*)carve((size_t)DALL * DCAT * 2);          // 51.4 MB
  bf16* w2t   = (bf16*)carve((size_t)DALL * DALL * 2);          // 25.7 MB
  bf16* pvb   = (bf16*)carve((size_t)NSLOT * DALL * 2);
  bf16* mvb   = (bf16*)carve((size_t)NSLOT * DALL * 2);
  bf16* pwTb  = (bf16*)carve((size_t)NPAIR * PDIM * MDIM * 2);
  bf16* att   = (bf16*)carve((size_t)B_SZ * 128 * 2);
  bf16* cvt   = (bf16*)carve((size_t)DALL * 128 * 2);
  float* part = (float*)carve((size_t)KSPLIT * DALL * 128 * 4); // 14.7 MB
  bf16* hpreb = (bf16*)carve((size_t)B_SZ * DALL * 2);          // 29.4 MB
  bf16* h2     = w1t;    // alias: w1t last read by precompute_cvt
  bf16* fusedb = hpreb;  // alias: hpreb last read by ln_gelu

  // weight converts
  tconv_kernel<<<dim3(DALL / 32, DCAT / 32, 1), 256, 0, stream>>>(w1, w1t, DCAT, DALL, 0, 0);
  tconv_kernel<<<dim3(DALL / 32, DALL / 32, 1), 256, 0, stream>>>(w2, w2t, DALL, DALL, 0, 0);
  tconv_kernel<<<dim3(PDIM / 32, MDIM / 32, NPAIR), 256, 0, stream>>>(
      pw, pwTb, MDIM, PDIM, MDIM * PDIM, MDIM * PDIM);
  conv_kernel<<<dim3(NSLOT * DALL / 2048), 256, 0, stream>>>(pval, pvb, NSLOT * DALL);
  conv_kernel<<<dim3(NSLOT * DALL / 2048), 256, 0, stream>>>(mval, mvb, NSLOT * DALL);
  // mean + softmax -> att[4096][128]; ps -> bf16
  prep_kernel<<<dim3(B_SZ), 256, 0, stream>>>(ps, mac, pkey, mkey, psb, att);
  // rank-128 factor: CVt = [w1t_top @ pv^T | w1t_bot @ mv^T]  (K-split)
  precompute_cvt<<<dim3(DALL / 256, 2, KSPLIT), 256, 0, stream>>>(w1t, pvb, mvb, part);
  reduce_cvt<<<dim3(DALL * 128 / 1024), 256, 0, stream>>>(part, cvt);
  // thin GEMM: hpre = att(4096x128) @ CVt^T + b1 -> bf16
  gemm_bt<1, 1><<<dim3(DALL / 128, B_SZ / 128), 256, 0, stream>>>(
      att, 128, cvt, hpreb, DALL, 0, b1, 128);
  ln_gelu_kernel<<<dim3(B_SZ), 256, 0, stream>>>(hpreb, lng1, lnb1, h2);
  // GEMM2: (4096 x 3584) @ (3584 x 3584)^T -> bf16 fused
  gemm8<1, 1><<<dim3((DALL / 256) * (B_SZ / 256)), 512, 0, stream>>>(
      h2, DALL, w2t, DALL, fusedb, DALL, b2, DALL, DALL / 256);
  pair_final<<<dim3(B_SZ / 128, NPAIR), 256, 0, stream>>>(
      psb, fusedb, pwTb, pb, plng, plnb, out);
}

// Round 5
// 293.631 us; speedup vs baseline: 2.4768x; 1.0579x over previous
//
#include <hip/hip_runtime.h>
#include <hip/hip_bf16.h>
#include <math.h>

// CrossPairMemory round 5: fuse w1 transpose/convert into the CVt precompute
// (reads fp32 w1 ONCE, in-LDS transpose; tconv_w1 + w1t buffer deleted).
// ps->bf16 moved to vectorized conv_kernel; prep mean reads bf16 psb.

#define B_SZ  4096
#define NPAIR 28
#define PDIM  128
#define MDIM  256
#define NSLOT 64
#define DALL  3584
#define DCAT  7168
#define KS2   16
#define KCH2  448   // DCAT / KS2

typedef __hip_bfloat16 bf16;
typedef __attribute__((ext_vector_type(8))) short bf16x8;
typedef __attribute__((ext_vector_type(4))) float f32x4;

#define BARRIER() asm volatile("s_barrier" ::: "memory")
#define VMCNT4()  asm volatile("s_waitcnt vmcnt(4)" ::: "memory")
#define VMCNT0()  asm volatile("s_waitcnt vmcnt(0)" ::: "memory")

__device__ __forceinline__ void async_copy16(void* lds, const void* g) {
  __builtin_amdgcn_global_load_lds((__attribute__((address_space(1))) void*)g,
                                   (__attribute__((address_space(3))) void*)lds,
                                   16, 0, 0);
}

// ============== 256x256x64 4-phase GEMM (r3/r4, verified) ==================
template <int OUT_BF16, int ADD_BIAS>
__global__ __launch_bounds__(512, 2)
void gemm8(const bf16* __restrict__ A, int lda, const bf16* __restrict__ Bt,
           int ldb, void* __restrict__ Cout, int ldc,
           const float* __restrict__ bias, int K, int nbx) {
  __shared__ __align__(16) char smem[131072];
  const int tid = threadIdx.x;
  const int wid = tid >> 6, lane = tid & 63;
  const int lr = lane & 15, lk = lane >> 4;
  const int wm = wid >> 2, wn = wid & 3;
  const int nwg = gridDim.x, cpx = nwg >> 3;
  const int swz = ((int)blockIdx.x & 7) * cpx + ((int)blockIdx.x >> 3);
  const int bx = swz % nbx, by = swz / nbx;
  const int col0 = bx * 256, row0 = by * 256;

  char* sA = smem;
  char* sB = smem + 65536;

  const int srow = tid >> 3;
  const int sg = (tid & 7) ^ (srow & 7);
  const bf16* aStage = A + (long)(row0 + srow) * lda + sg * 8;
  const bf16* bStage = Bt + (long)(col0 + srow) * ldb + sg * 8;
  const int wOff = wid << 10;

  const int NT = K >> 6;

  const int sx = lr & 7;
  const int arow = wm * 128 + lr;
  const int brow = wn * 64 + lr;

  f32x4 acc[8][4];
  const f32x4 zero = {0.f, 0.f, 0.f, 0.f};
#pragma unroll
  for (int m = 0; m < 8; ++m)
#pragma unroll
    for (int n = 0; n < 4; ++n) acc[m][n] = zero;

#pragma unroll
  for (int h = 0; h < 2; ++h) {
    const bf16* g = bStage + (long)h * 128 * ldb;
    char* d = sB + h * 16384 + wOff;
    async_copy16(d, g);
    async_copy16(d + 8192, g + 64 * ldb);
  }
#pragma unroll
  for (int h = 0; h < 2; ++h) {
    const bf16* g = aStage + (long)h * 128 * lda;
    char* d = sA + h * 16384 + wOff;
    async_copy16(d, g);
    async_copy16(d + 8192, g + 64 * lda);
  }
#pragma unroll
  for (int h = 0; h < 2; ++h) {
    const bf16* g = bStage + (long)h * 128 * ldb + 64;
    char* d = sB + 32768 + h * 16384 + wOff;
    async_copy16(d, g);
    async_copy16(d + 8192, g + 64 * ldb);
  }
  VMCNT4();
  BARRIER();

  bf16x8 af[4][2], bl[2][2], bh[2][2];

  for (int t = 0; t < NT; ++t) {
    const int buf = t & 1;
    char* cA = sA + buf * 32768;
    char* cB = sB + buf * 32768;
    char* nA = sA + (buf ^ 1) * 32768;

    if (t + 1 < NT) {
      const bf16* g = aStage + (long)(t + 1) * 64;
      async_copy16(nA + wOff, g);
      async_copy16(nA + 8192 + wOff, g + 64 * lda);
    }
#pragma unroll
    for (int m = 0; m < 4; ++m)
#pragma unroll
      for (int kk = 0; kk < 2; ++kk)
        af[m][kk] = *(const bf16x8*)(cA + (arow + m * 16) * 128 +
                                     ((((kk << 2) | lk) ^ sx) << 4));
#pragma unroll
    for (int n = 0; n < 2; ++n)
#pragma unroll
      for (int kk = 0; kk < 2; ++kk)
        bl[n][kk] = *(const bf16x8*)(cB + (brow + n * 16) * 128 +
                                     ((((kk << 2) | lk) ^ sx) << 4));
    __builtin_amdgcn_s_setprio(1);
#pragma unroll
    for (int m = 0; m < 4; ++m)
#pragma unroll
      for (int n = 0; n < 2; ++n)
#pragma unroll
        for (int kk = 0; kk < 2; ++kk)
          acc[m][n] = __builtin_amdgcn_mfma_f32_16x16x32_bf16(
              af[m][kk], bl[n][kk], acc[m][n], 0, 0, 0);
    __builtin_amdgcn_s_setprio(0);
    BARRIER();

    if (t + 1 < NT) {
      const bf16* g = aStage + (long)128 * lda + (long)(t + 1) * 64;
      async_copy16(nA + 16384 + wOff, g);
      async_copy16(nA + 16384 + 8192 + wOff, g + 64 * lda);
    }
#pragma unroll
    for (int n = 0; n < 2; ++n)
#pragma unroll
      for (int kk = 0; kk < 2; ++kk)
        bh[n][kk] = *(const bf16x8*)(cB + (brow + (n + 2) * 16) * 128 +
                                     ((((kk << 2) | lk) ^ sx) << 4));
    __builtin_amdgcn_s_setprio(1);
#pragma unroll
    for (int m = 0; m < 4; ++m)
#pragma unroll
      for (int n = 0; n < 2; ++n)
#pragma unroll
        for (int kk = 0; kk < 2; ++kk)
          acc[m][n + 2] = __builtin_amdgcn_mfma_f32_16x16x32_bf16(
              af[m][kk], bh[n][kk], acc[m][n + 2], 0, 0, 0);
    __builtin_amdgcn_s_setprio(0);
    BARRIER();

    if (t + 2 < NT) {
      const bf16* g = bStage + (long)(t + 2) * 64;
      async_copy16(cB + wOff, g);
      async_copy16(cB + 8192 + wOff, g + 64 * ldb);
    }
#pragma unroll
    for (int m = 0; m < 4; ++m)
#pragma unroll
      for (int kk = 0; kk < 2; ++kk)
        af[m][kk] = *(const bf16x8*)(cA + (arow + (m + 4) * 16) * 128 +
                                     ((((kk << 2) | lk) ^ sx) << 4));
    __builtin_amdgcn_s_setprio(1);
#pragma unroll
    for (int m = 0; m < 4; ++m)
#pragma unroll
      for (int n = 0; n < 2; ++n)
#pragma unroll
        for (int kk = 0; kk < 2; ++kk)
          acc[m + 4][n] = __builtin_amdgcn_mfma_f32_16x16x32_bf16(
              af[m][kk], bl[n][kk], acc[m + 4][n], 0, 0, 0);
    __builtin_amdgcn_s_setprio(0);
    BARRIER();

    const int more = (t + 2 < NT);
    if (more) {
      const bf16* g = bStage + (long)128 * ldb + (long)(t + 2) * 64;
      async_copy16(cB + 16384 + wOff, g);
      async_copy16(cB + 16384 + 8192 + wOff, g + 64 * ldb);
    }
    __builtin_amdgcn_s_setprio(1);
#pragma unroll
    for (int m = 0; m < 4; ++m)
#pragma unroll
      for (int n = 0; n < 2; ++n)
#pragma unroll
        for (int kk = 0; kk < 2; ++kk)
          acc[m + 4][n + 2] = __builtin_amdgcn_mfma_f32_16x16x32_bf16(
              af[m][kk], bh[n][kk], acc[m + 4][n + 2], 0, 0, 0);
    __builtin_amdgcn_s_setprio(0);
    if (more) { VMCNT4(); } else { VMCNT0(); }
    BARRIER();
  }

#pragma unroll
  for (int m = 0; m < 8; ++m) {
#pragma unroll
    for (int n = 0; n < 4; ++n) {
      const int gc = col0 + wn * 64 + n * 16 + lr;
      const float bia = ADD_BIAS ? bias[gc] : 0.f;
#pragma unroll
      for (int j = 0; j < 4; ++j) {
        const int gr = row0 + wm * 128 + m * 16 + lk * 4 + j;
        const float v = acc[m][n][j] + bia;
        const long off = (long)gr * ldc + gc;
        if (OUT_BF16)
          ((bf16*)Cout)[off] = __float2bfloat16(v);
        else
          ((float*)Cout)[off] = v;
      }
    }
  }
}

// ---------------- transpose + fp32->bf16 convert (w2, pw) ------------------
__global__ __launch_bounds__(256)
void tconv_kernel(const float* __restrict__ in, bf16* __restrict__ out,
                  int R, int C, int inBatch, int outBatch) {
  __shared__ float tile[32][33];
  const int tid = threadIdx.x;
  const int tx = tid & 31, ty = tid >> 5;
  const long ib = (long)blockIdx.z * inBatch;
  const long ob = (long)blockIdx.z * outBatch;
  const int c0 = blockIdx.x * 32, r0 = blockIdx.y * 32;
#pragma unroll
  for (int i = 0; i < 4; ++i)
    tile[ty + i * 8][tx] = in[ib + (long)(r0 + ty + i * 8) * C + c0 + tx];
  __syncthreads();
#pragma unroll
  for (int i = 0; i < 4; ++i)
    out[ob + (long)(c0 + ty + i * 8) * R + r0 + tx] =
        __float2bfloat16(tile[tx][ty + i * 8]);
}

// ---------------- plain fp32->bf16 convert ---------------------------------
__global__ __launch_bounds__(256)
void conv_kernel(const float* __restrict__ in, bf16* __restrict__ out, int n) {
  const int i = (blockIdx.x * 256 + threadIdx.x) * 8;
  if (i + 7 < n) {
    float4 a = *(const float4*)(in + i);
    float4 b = *(const float4*)(in + i + 4);
    bf16 o[8];
    o[0] = __float2bfloat16(a.x); o[1] = __float2bfloat16(a.y);
    o[2] = __float2bfloat16(a.z); o[3] = __float2bfloat16(a.w);
    o[4] = __float2bfloat16(b.x); o[5] = __float2bfloat16(b.y);
    o[6] = __float2bfloat16(b.z); o[7] = __float2bfloat16(b.w);
    *(bf16x8*)(out + i) = *(bf16x8*)o;
  }
}

// ---------------- prep: pair mean (from bf16 psb) -> softmax scores --------
__global__ __launch_bounds__(256)
void prep_kernel(const bf16* __restrict__ psb, const float* __restrict__ mac,
                 const float* __restrict__ pkeys, const float* __restrict__ mkeys,
                 bf16* __restrict__ att) {
  const int b = blockIdx.x, tid = threadIdx.x;
  __shared__ float q[PDIM];
  __shared__ float mrow[MDIM];
  if (tid < MDIM) mrow[tid] = mac[(long)b * MDIM + tid];
  if (tid < PDIM) {
    const bf16* prow = psb + (long)b * DALL + tid;
    float s = 0.f;
#pragma unroll
    for (int p = 0; p < NPAIR; ++p) s += __bfloat162float(prow[p * PDIM]);
    q[tid] = s * (1.f / NPAIR);
  }
  __syncthreads();
  const int wid = tid >> 6, lane = tid & 63;
  if (wid == 0) {
    float sc = 0.f;
    const float* kr = pkeys + lane * PDIM;
    for (int d = 0; d < PDIM; ++d) sc += q[d] * kr[d];
    sc *= 0.08838834764831845f;
    float mx = sc;
#pragma unroll
    for (int m = 32; m; m >>= 1) mx = fmaxf(mx, __shfl_xor(mx, m));
    float e = expf(sc - mx);
    float ssum = e;
#pragma unroll
    for (int m = 32; m; m >>= 1) ssum += __shfl_xor(ssum, m);
    att[(long)b * 128 + lane] = __float2bfloat16(e / ssum);
  } else if (wid == 1) {
    float sc = 0.f;
    const float* kr = mkeys + lane * MDIM;
    for (int d = 0; d < MDIM; ++d) sc += mrow[d] * kr[d];
    sc *= 0.0625f;
    float mx = sc;
#pragma unroll
    for (int m = 32; m; m >>= 1) mx = fmaxf(mx, __shfl_xor(mx, m));
    float e = expf(sc - mx);
    float ssum = e;
#pragma unroll
    for (int m = 32; m; m >>= 1) ssum += __shfl_xor(ssum, m);
    att[(long)b * 128 + 64 + lane] = __float2bfloat16(e / ssum);
  }
}

// ---------------- CVt precompute DIRECT from fp32 w1 -----------------------
// part[ksb][n][s] = sum_{k in chunk ksb} w1[k][n] * vals[s][k-koff]
// w1 fp32 [7168][3584] read once; 256n x 32k block transposed+converted in
// LDS (pad 40 -> 16B-aligned b128 rows). vals already bf16 (pvb/mvb).
// grid (14 n-blocks, KS2=16 k-chunks); chunks 0-7 pair half, 8-15 macro.
__global__ __launch_bounds__(256)
void precompute_direct(const float* __restrict__ w1, const bf16* __restrict__ pvb,
                       const bf16* __restrict__ mvb, float* __restrict__ part) {
  __shared__ __align__(16) bf16 sAt[256 * 40];
  __shared__ __align__(16) bf16 sBt[64 * 32];
  const int tid = threadIdx.x, wid = tid >> 6, lane = tid & 63;
  const int lr = lane & 15, lk = lane >> 4;
  const int n0 = blockIdx.x * 256;
  const int ksb = blockIdx.y;
  const int kbase = ksb * KCH2;
  const bf16* vb = (ksb < 8) ? pvb : mvb;
  const int kcol0 = (ksb < 8) ? kbase : kbase - DALL;

  const int bs = tid >> 2;           // B staging: slot row 0..63
  const int bgs = (tid & 3) ^ (bs & 3);  // pre-swizzled source granule

  f32x4 acc[4][4];
  const f32x4 zero = {0.f, 0.f, 0.f, 0.f};
#pragma unroll
  for (int m = 0; m < 4; ++m)
#pragma unroll
    for (int n = 0; n < 4; ++n) acc[m][n] = zero;

  for (int kt = 0; kt < KCH2; kt += 32) {
    __syncthreads();
    // A: transpose+convert w1[kbase+kt .. +31][n0+tid] -> sAt[tid][0..31]
    {
      const float* src = w1 + (long)(kbase + kt) * DALL + n0 + tid;
      bf16* dst = sAt + tid * 40;
#pragma unroll
      for (int r = 0; r < 32; ++r)
        dst[r] = __float2bfloat16(src[(long)r * DALL]);
    }
    // B: gload_lds linear dest, source granule-swizzled
    async_copy16((char*)sBt + tid * 16,
                 vb + (long)bs * DALL + kcol0 + kt + bgs * 8);
    __syncthreads();
    bf16x8 af[4], bfr[4];
#pragma unroll
    for (int m = 0; m < 4; ++m)
      af[m] = *(const bf16x8*)((const char*)sAt +
                               ((wid * 64 + m * 16 + lr) * 40 + lk * 8) * 2);
#pragma unroll
    for (int n = 0; n < 4; ++n) {
      const int s = n * 16 + lr;
      bfr[n] = *(const bf16x8*)((const char*)sBt + s * 64 + ((lk ^ (s & 3)) << 4));
    }
#pragma unroll
    for (int m = 0; m < 4; ++m)
#pragma unroll
      for (int n = 0; n < 4; ++n)
        acc[m][n] =
            __builtin_amdgcn_mfma_f32_16x16x32_bf16(af[m], bfr[n], acc[m][n], 0, 0, 0);
  }
#pragma unroll
  for (int m = 0; m < 4; ++m)
#pragma unroll
    for (int n = 0; n < 4; ++n)
#pragma unroll
      for (int j = 0; j < 4; ++j) {
        const int gn = n0 + wid * 64 + m * 16 + lk * 4 + j;
        const int s = n * 16 + lr;
        part[((long)ksb * DALL + gn) * 64 + s] = acc[m][n][j];
      }
}

// ---------------- reduce K-split partials -> CVt bf16 [3584][128] ---------
// cvt[n][s<64] = sum_{j=0..7} part[j][n][s]; cvt[n][64+s] = sum_{j=8..15}.
__global__ __launch_bounds__(256)
void reduce_cvt(const float* __restrict__ part, bf16* __restrict__ cvt) {
  const long i4 = ((long)blockIdx.x * 256 + threadIdx.x) * 4;
  const int n = (int)(i4 >> 7), sc = (int)(i4 & 127);
  const int half = sc >> 6, s0 = sc & 63;
  f32x4 s = {0.f, 0.f, 0.f, 0.f};
#pragma unroll
  for (int j = 0; j < 8; ++j)
    s += *(const f32x4*)(part + ((long)(half * 8 + j) * DALL + n) * 64 + s0);
#pragma unroll
  for (int k = 0; k < 4; ++k) cvt[i4 + k] = __float2bfloat16(s[k]);
}

// ---------------- 128x128 2-barrier GEMM (thin K) --------------------------
template <int OUT_BF16, int ADD_BIAS>
__global__ __launch_bounds__(256)
void gemm_bt(const bf16* __restrict__ A, int lda, const bf16* __restrict__ Bt,
             void* __restrict__ Cout, int ldc, int col_off,
             const float* __restrict__ bias, int K) {
  __shared__ __align__(16) bf16 sA[128 * 32];
  __shared__ __align__(16) bf16 sB[128 * 32];
  const int tid = threadIdx.x;
  const int wid = tid >> 6, lane = tid & 63;
  const int lr = lane & 15, lk = lane >> 4;
  const int col0 = blockIdx.x * 128, row0 = blockIdx.y * 128;
  const int wrow = (wid >> 1) * 64, wcol = (wid & 1) * 64;
  const int ea = tid * 8;
  const int ra = ea >> 5, ca = ea & 31;

  f32x4 acc[4][4];
  const f32x4 zero = {0.f, 0.f, 0.f, 0.f};
#pragma unroll
  for (int m = 0; m < 4; ++m)
#pragma unroll
    for (int n = 0; n < 4; ++n) acc[m][n] = zero;

  const long aBase = (long)row0 * lda;
  const long bBase = (long)col0 * K;
  char* sAb = (char*)sA;
  char* sBb = (char*)sB;
  const int wOff = wid * 1024;

  for (int kt = 0; kt < K; kt += 32) {
    __syncthreads();
#pragma unroll
    for (int i = 0; i < 2; ++i) {
      async_copy16(sAb + i * 4096 + wOff,
                   A + aBase + (long)(ra + i * 64) * lda + kt + ca);
      async_copy16(sBb + i * 4096 + wOff,
                   Bt + bBase + (long)(ra + i * 64) * K + kt + ca);
    }
    __syncthreads();
    bf16x8 af[4], bfr[4];
    const bf16x8* pA = (const bf16x8*)sA;
    const bf16x8* pB = (const bf16x8*)sB;
#pragma unroll
    for (int m = 0; m < 4; ++m) af[m] = pA[(wrow + m * 16 + lr) * 4 + lk];
#pragma unroll
    for (int n = 0; n < 4; ++n) bfr[n] = pB[(wcol + n * 16 + lr) * 4 + lk];
#pragma unroll
    for (int m = 0; m < 4; ++m)
#pragma unroll
      for (int n = 0; n < 4; ++n)
        acc[m][n] =
            __builtin_amdgcn_mfma_f32_16x16x32_bf16(af[m], bfr[n], acc[m][n], 0, 0, 0);
  }
#pragma unroll
  for (int m = 0; m < 4; ++m) {
#pragma unroll
    for (int n = 0; n < 4; ++n) {
      const int gcl = col0 + wcol + n * 16 + lr;
      const float bia = ADD_BIAS ? bias[gcl] : 0.f;
#pragma unroll
      for (int j = 0; j < 4; ++j) {
        const int gr = row0 + wrow + m * 16 + lk * 4 + j;
        const float v = acc[m][n][j] + bia;
        const long off = (long)gr * ldc + col_off + gcl;
        if (OUT_BF16)
          ((bf16*)Cout)[off] = __float2bfloat16(v);
        else
          ((float*)Cout)[off] = v;
      }
    }
  }
}

// ---------------- LayerNorm + exact GELU, bf16 in -> bf16 out -------------
__global__ __launch_bounds__(256)
void ln_gelu_kernel(const bf16* __restrict__ h, const float* __restrict__ g,
                    const float* __restrict__ bb, bf16* __restrict__ h2) {
  const int row = blockIdx.x, tid = threadIdx.x;
  const bf16* x = h + (long)row * DALL;
  float v[14];
  float s1 = 0.f, s2 = 0.f;
#pragma unroll
  for (int i = 0; i < 14; ++i) {
    v[i] = __bfloat162float(x[i * 256 + tid]);
    s1 += v[i];
    s2 += v[i] * v[i];
  }
#pragma unroll
  for (int m = 32; m; m >>= 1) {
    s1 += __shfl_xor(s1, m);
    s2 += __shfl_xor(s2, m);
  }
  __shared__ float r1[4], r2[4];
  const int wid = tid >> 6, lane = tid & 63;
  if (lane == 0) {
    r1[wid] = s1;
    r2[wid] = s2;
  }
  __syncthreads();
  s1 = r1[0] + r1[1] + r1[2] + r1[3];
  s2 = r2[0] + r2[1] + r2[2] + r2[3];
  const float mean = s1 * (1.f / DALL);
  const float var = s2 * (1.f / DALL) - mean * mean;
  const float rstd = rsqrtf(var + 1e-5f);
#pragma unroll
  for (int i = 0; i < 14; ++i) {
    const int c = i * 256 + tid;
    const float y = (v[i] - mean) * rstd * g[c] + bb[c];
    const float ge = 0.5f * y * (1.f + erff(y * 0.7071067811865475f));
    h2[(long)row * DALL + c] = __float2bfloat16(ge);
  }
}

// ---------------- per-pair GEMM (K=256) + LayerNorm epilogue --------------
__global__ __launch_bounds__(256)
void pair_final(const bf16* __restrict__ psb, const bf16* __restrict__ fusedb,
                const bf16* __restrict__ pwT, const float* __restrict__ pb,
                const float* __restrict__ lng, const float* __restrict__ lnb,
                float* __restrict__ out) {
  __shared__ __align__(16) bf16 sA[128 * 32];
  __shared__ __align__(16) bf16 sB[128 * 32];
  const int tid = threadIdx.x, wid = tid >> 6, lane = tid & 63;
  const int lr = lane & 15, lk = lane >> 4;
  const int p = blockIdx.y, row0 = blockIdx.x * 128;
  const int ea = tid * 8, ra = ea >> 5, ca = ea & 31;

  f32x4 acc[2][8];
  const f32x4 zero = {0.f, 0.f, 0.f, 0.f};
#pragma unroll
  for (int m = 0; m < 2; ++m)
#pragma unroll
    for (int n = 0; n < 8; ++n) acc[m][n] = zero;

  const bf16* pwp = pwT + (long)p * (PDIM * MDIM);
  char* sAb = (char*)sA;
  char* sBb = (char*)sB;
  const int wOff = wid * 1024;

  for (int kt = 0; kt < MDIM; kt += 32) {
    __syncthreads();
    const bf16* Asrc = (kt < PDIM) ? psb : fusedb;
    const int kc = kt & (PDIM - 1);
#pragma unroll
    for (int i = 0; i < 2; ++i) {
      async_copy16(sAb + i * 4096 + wOff,
                   Asrc + (long)(row0 + ra + i * 64) * DALL + p * PDIM + kc + ca);
      async_copy16(sBb + i * 4096 + wOff, pwp + (ra + i * 64) * MDIM + kt + ca);
    }
    __syncthreads();
    bf16x8 af[2], bfr[8];
    const bf16x8* pA = (const bf16x8*)sA;
    const bf16x8* pB = (const bf16x8*)sB;
#pragma unroll
    for (int m = 0; m < 2; ++m) af[m] = pA[(wid * 32 + m * 16 + lr) * 4 + lk];
#pragma unroll
    for (int n = 0; n < 8; ++n) bfr[n] = pB[(n * 16 + lr) * 4 + lk];
#pragma unroll
    for (int m = 0; m < 2; ++m)
#pragma unroll
      for (int n = 0; n < 8; ++n)
        acc[m][n] =
            __builtin_amdgcn_mfma_f32_16x16x32_bf16(af[m], bfr[n], acc[m][n], 0, 0, 0);
  }
  float g_[8], b_[8], pb_[8];
#pragma unroll
  for (int n = 0; n < 8; ++n) {
    const int c = n * 16 + lr;
    g_[n] = lng[p * PDIM + c];
    b_[n] = lnb[p * PDIM + c];
    pb_[n] = pb[p * PDIM + c];
  }
#pragma unroll
  for (int m = 0; m < 2; ++m) {
#pragma unroll
    for (int j = 0; j < 4; ++j) {
      float vv[8];
      float s1 = 0.f, s2 = 0.f;
#pragma unroll
      for (int n = 0; n < 8; ++n) {
        vv[n] = acc[m][n][j] + pb_[n];
        s1 += vv[n];
        s2 += vv[n] * vv[n];
      }
#pragma unroll
      for (int msk = 1; msk <= 8; msk <<= 1) {
        s1 += __shfl_xor(s1, msk);
        s2 += __shfl_xor(s2, msk);
      }
      const float mean = s1 * (1.f / 128.f);
      const float var = s2 * (1.f / 128.f) - mean * mean;
      const float rstd = rsqrtf(var + 1e-5f);
      const int gr = row0 + wid * 32 + m * 16 + lk * 4 + j;
      float* orow = out + ((long)gr * NPAIR + p) * PDIM;
#pragma unroll
      for (int n = 0; n < 8; ++n)
        orow[n * 16 + lr] = (vv[n] - mean) * rstd * g_[n] + b_[n];
    }
  }
}

// ---------------------------------------------------------------------------
extern "C" void kernel_launch(void* const* d_in, const int* in_sizes, int n_in,
                              void* d_out, int out_size, void* d_ws, size_t ws_size,
                              hipStream_t stream) {
  (void)in_sizes; (void)n_in; (void)out_size; (void)ws_size;
  const float* ps   = (const float*)d_in[0];
  const float* mac  = (const float*)d_in[1];
  const float* pkey = (const float*)d_in[2];
  const float* pval = (const float*)d_in[3];
  const float* mkey = (const float*)d_in[4];
  const float* mval = (const float*)d_in[5];
  const float* w1   = (const float*)d_in[6];
  const float* b1   = (const float*)d_in[7];
  const float* lng1 = (const float*)d_in[8];
  const float* lnb1 = (const float*)d_in[9];
  const float* w2   = (const float*)d_in[10];
  const float* b2   = (const float*)d_in[11];
  const float* pw   = (const float*)d_in[12];
  const float* pb   = (const float*)d_in[13];
  const float* plng = (const float*)d_in[14];
  const float* plnb = (const float*)d_in[15];
  float* out = (float*)d_out;

  char* w = (char*)d_ws;
  size_t off = 0;
  auto carve = [&](size_t bytes) {
    char* pp = w + off;
    off += (bytes + 255) & ~(size_t)255;
    return pp;
  };
  bf16* psb   = (bf16*)carve((size_t)B_SZ * DALL * 2);           // 29.4 MB
  bf16* w2t   = (bf16*)carve((size_t)DALL * DALL * 2);           // 25.7 MB
  bf16* pvb   = (bf16*)carve((size_t)NSLOT * DALL * 2);
  bf16* mvb   = (bf16*)carve((size_t)NSLOT * DALL * 2);
  bf16* pwTb  = (bf16*)carve((size_t)NPAIR * PDIM * MDIM * 2);
  bf16* att   = (bf16*)carve((size_t)B_SZ * 128 * 2);
  bf16* cvt   = (bf16*)carve((size_t)DALL * 128 * 2);
  float* part = (float*)carve((size_t)KS2 * DALL * 64 * 4);      // 14.7 MB
  bf16* hpreb = (bf16*)carve((size_t)B_SZ * DALL * 2);           // 29.4 MB
  bf16* h2    = (bf16*)carve((size_t)B_SZ * DALL * 2);           // 29.4 MB
  bf16* fusedb = hpreb;  // alias: hpreb last read by ln_gelu

  // converts
  conv_kernel<<<dim3(B_SZ * DALL / 2048), 256, 0, stream>>>(ps, psb, B_SZ * DALL);
  conv_kernel<<<dim3(NSLOT * DALL / 2048), 256, 0, stream>>>(pval, pvb, NSLOT * DALL);
  conv_kernel<<<dim3(NSLOT * DALL / 2048), 256, 0, stream>>>(mval, mvb, NSLOT * DALL);
  tconv_kernel<<<dim3(DALL / 32, DALL / 32, 1), 256, 0, stream>>>(w2, w2t, DALL, DALL, 0, 0);
  tconv_kernel<<<dim3(PDIM / 32, MDIM / 32, NPAIR), 256, 0, stream>>>(
      pw, pwTb, MDIM, PDIM, MDIM * PDIM, MDIM * PDIM);
  // mean + softmax -> att[4096][128]
  prep_kernel<<<dim3(B_SZ), 256, 0, stream>>>(psb, mac, pkey, mkey, att);
  // rank-128 factor directly from fp32 w1 (read once, in-LDS transpose)
  precompute_direct<<<dim3(DALL / 256, KS2), 256, 0, stream>>>(w1, pvb, mvb, part);
  reduce_cvt<<<dim3(DALL * 128 / 1024), 256, 0, stream>>>(part, cvt);
  // thin GEMM: hpre = att(4096x128) @ CVt^T + b1 -> bf16
  gemm_bt<1, 1><<<dim3(DALL / 128, B_SZ / 128), 256, 0, stream>>>(
      att, 128, cvt, hpreb, DALL, 0, b1, 128);
  ln_gelu_kernel<<<dim3(B_SZ), 256, 0, stream>>>(hpreb, lng1, lnb1, h2);
  // GEMM2: (4096 x 3584) @ (3584 x 3584)^T -> bf16 fused
  gemm8<1, 1><<<dim3((DALL / 256) * (B_SZ / 256)), 512, 0, stream>>>(
      h2, DALL, w2t, DALL, fusedb, DALL, b2, DALL, DALL / 256);
  pair_final<<<dim3(B_SZ / 128, NPAIR), 256, 0, stream>>>(
      psb, fusedb, pwTb, pb, plng, plnb, out);
}

// Round 6
// 283.916 us; speedup vs baseline: 2.5615x; 1.0342x over previous
//
#include <hip/hip_runtime.h>
#include <hip/hip_bf16.h>
#include <math.h>

// CrossPairMemory round 6: GEMM2 -> gemm224 (BN=224, grid 16x16=256 full CU
// fill, 2-phase schedule, B-LDS padded to 256 rows). prep re-fused (reads
// fp32 ps once, writes psb+att). val converts merged into one launch.

#define B_SZ  4096
#define NPAIR 28
#define PDIM  128
#define MDIM  256
#define NSLOT 64
#define DALL  3584
#define DCAT  7168
#define KS2   16
#define KCH2  448   // DCAT / KS2

typedef __hip_bfloat16 bf16;
typedef __attribute__((ext_vector_type(8))) short bf16x8;
typedef __attribute__((ext_vector_type(4))) float f32x4;

#define BARRIER() asm volatile("s_barrier" ::: "memory")
#define LGKM0()   asm volatile("s_waitcnt lgkmcnt(0)" ::: "memory")
#define VMCNT4()  asm volatile("s_waitcnt vmcnt(4)" ::: "memory")
#define VMCNT0()  asm volatile("s_waitcnt vmcnt(0)" ::: "memory")

__device__ __forceinline__ void async_copy16(void* lds, const void* g) {
  __builtin_amdgcn_global_load_lds((__attribute__((address_space(1))) void*)g,
                                   (__attribute__((address_space(3))) void*)lds,
                                   16, 0, 0);
}

// ============== 256x224x64 2-phase GEMM: C = A * Bt^T + bias (bf16 out) ====
// 512 thr = 8 waves (4M x 2N). Wave tile 64x112 = 4x7 16x16 frags.
// LDS 128KB: A dbuf 2x32KB @0; B dbuf 2x32KB @64KB (B padded 224->256 rows;
// rows 224-255 staged from padded w2t tail, never read). Swizzle
// granule^=(row&7) on pre-swizzled global source + ds_read (r2: 0 conflicts).
// p0: stage A(t+1)->other buf; read a(8)+b(14); MFMA n0-3 (32); LGKM0; BAR.
// p1: stage B(t+2)->cur buf (reads drained at p0 bar); MFMA n4-6 (24);
//     vmcnt(4) [leaves exactly B(t+2) in flight]; BAR.
__global__ __launch_bounds__(512, 2)
void gemm224(const bf16* __restrict__ A, const bf16* __restrict__ Bt,
             bf16* __restrict__ Cout, const float* __restrict__ bias) {
  __shared__ __align__(16) char smem[131072];
  const int tid = threadIdx.x;
  const int wid = tid >> 6, lane = tid & 63;
  const int lr = lane & 15, lk = lane >> 4;
  const int wm = wid >> 1, wn = wid & 1;
  // XCD-bijective swizzle, grid 256 (16x16)
  const int swz = ((int)blockIdx.x & 7) * 32 + ((int)blockIdx.x >> 3);
  const int bx = swz & 15, by = swz >> 4;
  const int col0 = bx * 224, row0 = by * 256;

  char* sA = smem;            // 2 x 32KB
  char* sB = smem + 65536;    // 2 x 32KB (256 rows x 128B)

  const int srow = tid >> 3;
  const int sg = (tid & 7) ^ (srow & 7);
  const bf16* aStage = A + (long)(row0 + srow) * DALL + sg * 8;
  const bf16* bStage = Bt + (long)(col0 + srow) * DALL + sg * 8;
  const int wOff = wid << 10;

  const int NT = DALL >> 6;  // 56

  const int sx = lr & 7;
  const int arowb = wm * 64 + lr;
  const int browb = wn * 112 + lr;

  f32x4 acc[4][7];
  const f32x4 zero = {0.f, 0.f, 0.f, 0.f};
#pragma unroll
  for (int m = 0; m < 4; ++m)
#pragma unroll
    for (int n = 0; n < 7; ++n) acc[m][n] = zero;

  // ---- prologue: B(0)->buf0, A(0)->buf0, B(1)->buf1 (4 issues each)
#pragma unroll
  for (int i = 0; i < 4; ++i)
    async_copy16(sB + i * 8192 + wOff, bStage + (long)i * 64 * DALL);
#pragma unroll
  for (int i = 0; i < 4; ++i)
    async_copy16(sA + i * 8192 + wOff, aStage + (long)i * 64 * DALL);
#pragma unroll
  for (int i = 0; i < 4; ++i)
    async_copy16(sB + 32768 + i * 8192 + wOff, bStage + (long)i * 64 * DALL + 64);
  VMCNT4();  // B(0)+A(0) landed; B(1) in flight
  BARRIER();

  bf16x8 af[4][2], bf[7][2];

  for (int t = 0; t < NT; ++t) {
    const int cur = t & 1;
    char* cA = sA + cur * 32768;
    char* cB = sB + cur * 32768;
    char* nA = sA + (cur ^ 1) * 32768;

    // ---------------- p0
    if (t + 1 < NT) {
      const bf16* g = aStage + (long)(t + 1) * 64;
#pragma unroll
      for (int i = 0; i < 4; ++i)
        async_copy16(nA + i * 8192 + wOff, g + (long)i * 64 * DALL);
    }
#pragma unroll
    for (int m = 0; m < 4; ++m)
#pragma unroll
      for (int kk = 0; kk < 2; ++kk)
        af[m][kk] = *(const bf16x8*)(cA + (arowb + m * 16) * 128 +
                                     ((((kk << 2) | lk) ^ sx) << 4));
#pragma unroll
    for (int n = 0; n < 7; ++n)
#pragma unroll
      for (int kk = 0; kk < 2; ++kk)
        bf[n][kk] = *(const bf16x8*)(cB + (browb + n * 16) * 128 +
                                     ((((kk << 2) | lk) ^ sx) << 4));
    __builtin_amdgcn_s_setprio(1);
#pragma unroll
    for (int m = 0; m < 4; ++m)
#pragma unroll
      for (int n = 0; n < 4; ++n)
#pragma unroll
        for (int kk = 0; kk < 2; ++kk)
          acc[m][n] = __builtin_amdgcn_mfma_f32_16x16x32_bf16(
              af[m][kk], bf[n][kk], acc[m][n], 0, 0, 0);
    __builtin_amdgcn_s_setprio(0);
    LGKM0();   // all 22 reads retired before any wave crosses the barrier
    BARRIER();

    // ---------------- p1
    const int more = (t + 2 < NT);
    if (more) {
      const bf16* g = bStage + (long)(t + 2) * 64;
#pragma unroll
      for (int i = 0; i < 4; ++i)
        async_copy16(cB + i * 8192 + wOff, g + (long)i * 64 * DALL);
    }
    __builtin_amdgcn_s_setprio(1);
#pragma unroll
    for (int m = 0; m < 4; ++m)
#pragma unroll
      for (int n = 4; n < 7; ++n)
#pragma unroll
        for (int kk = 0; kk < 2; ++kk)
          acc[m][n] = __builtin_amdgcn_mfma_f32_16x16x32_bf16(
              af[m][kk], bf[n][kk], acc[m][n], 0, 0, 0);
    __builtin_amdgcn_s_setprio(0);
    if (more) { VMCNT4(); } else { VMCNT0(); }
    BARRIER();
  }

  // ---- epilogue
#pragma unroll
  for (int m = 0; m < 4; ++m) {
#pragma unroll
    for (int n = 0; n < 7; ++n) {
      const int gc = col0 + wn * 112 + n * 16 + lr;
      const float bia = bias[gc];
#pragma unroll
      for (int j = 0; j < 4; ++j) {
        const int gr = row0 + wm * 64 + m * 16 + lk * 4 + j;
        Cout[(long)gr * DALL + gc] = __float2bfloat16(acc[m][n][j] + bia);
      }
    }
  }
}

// ---------------- transpose + fp32->bf16 convert (w2, pw) ------------------
__global__ __launch_bounds__(256)
void tconv_kernel(const float* __restrict__ in, bf16* __restrict__ out,
                  int R, int C, int inBatch, int outBatch) {
  __shared__ float tile[32][33];
  const int tid = threadIdx.x;
  const int tx = tid & 31, ty = tid >> 5;
  const long ib = (long)blockIdx.z * inBatch;
  const long ob = (long)blockIdx.z * outBatch;
  const int c0 = blockIdx.x * 32, r0 = blockIdx.y * 32;
#pragma unroll
  for (int i = 0; i < 4; ++i)
    tile[ty + i * 8][tx] = in[ib + (long)(r0 + ty + i * 8) * C + c0 + tx];
  __syncthreads();
#pragma unroll
  for (int i = 0; i < 4; ++i)
    out[ob + (long)(c0 + ty + i * 8) * R + r0 + tx] =
        __float2bfloat16(tile[tx][ty + i * 8]);
}

// ---------------- fp32->bf16 convert for pair_vals + macro_vals ------------
__global__ __launch_bounds__(256)
void conv2_kernel(const float* __restrict__ pv, const float* __restrict__ mv,
                  bf16* __restrict__ pvb, bf16* __restrict__ mvb) {
  const float* in = blockIdx.y ? mv : pv;
  bf16* out = blockIdx.y ? mvb : pvb;
  const int i = (blockIdx.x * 256 + threadIdx.x) * 8;
  float4 a = *(const float4*)(in + i);
  float4 b = *(const float4*)(in + i + 4);
  bf16 o[8];
  o[0] = __float2bfloat16(a.x); o[1] = __float2bfloat16(a.y);
  o[2] = __float2bfloat16(a.z); o[3] = __float2bfloat16(a.w);
  o[4] = __float2bfloat16(b.x); o[5] = __float2bfloat16(b.y);
  o[6] = __float2bfloat16(b.z); o[7] = __float2bfloat16(b.w);
  *(bf16x8*)(out + i) = *(bf16x8*)o;
}

// ---------------- prep: ps->bf16 + pair mean -> softmax scores -------------
__global__ __launch_bounds__(256)
void prep_kernel(const float* __restrict__ ps, const float* __restrict__ mac,
                 const float* __restrict__ pkeys, const float* __restrict__ mkeys,
                 bf16* __restrict__ psb, bf16* __restrict__ att) {
  const int b = blockIdx.x, tid = threadIdx.x;
  __shared__ float q[PDIM];
  __shared__ float mrow[MDIM];
  const float* prow = ps + (long)b * DALL;
  if (tid < MDIM) mrow[tid] = mac[(long)b * MDIM + tid];
  if (tid < PDIM) {
    float s = 0.f;
#pragma unroll
    for (int p = 0; p < NPAIR; ++p) s += prow[p * PDIM + tid];
    q[tid] = s * (1.f / NPAIR);
  }
  for (int i = tid; i < DALL; i += 256)
    psb[(long)b * DALL + i] = __float2bfloat16(prow[i]);
  __syncthreads();
  const int wid = tid >> 6, lane = tid & 63;
  if (wid == 0) {
    float sc = 0.f;
    const float* kr = pkeys + lane * PDIM;
    for (int d = 0; d < PDIM; ++d) sc += q[d] * kr[d];
    sc *= 0.08838834764831845f;
    float mx = sc;
#pragma unroll
    for (int m = 32; m; m >>= 1) mx = fmaxf(mx, __shfl_xor(mx, m));
    float e = expf(sc - mx);
    float ssum = e;
#pragma unroll
    for (int m = 32; m; m >>= 1) ssum += __shfl_xor(ssum, m);
    att[(long)b * 128 + lane] = __float2bfloat16(e / ssum);
  } else if (wid == 1) {
    float sc = 0.f;
    const float* kr = mkeys + lane * MDIM;
    for (int d = 0; d < MDIM; ++d) sc += mrow[d] * kr[d];
    sc *= 0.0625f;
    float mx = sc;
#pragma unroll
    for (int m = 32; m; m >>= 1) mx = fmaxf(mx, __shfl_xor(mx, m));
    float e = expf(sc - mx);
    float ssum = e;
#pragma unroll
    for (int m = 32; m; m >>= 1) ssum += __shfl_xor(ssum, m);
    att[(long)b * 128 + 64 + lane] = __float2bfloat16(e / ssum);
  }
}

// ---------------- CVt precompute DIRECT from fp32 w1 (r5, verified) --------
__global__ __launch_bounds__(256)
void precompute_direct(const float* __restrict__ w1, const bf16* __restrict__ pvb,
                       const bf16* __restrict__ mvb, float* __restrict__ part) {
  __shared__ __align__(16) bf16 sAt[256 * 40];
  __shared__ __align__(16) bf16 sBt[64 * 32];
  const int tid = threadIdx.x, wid = tid >> 6, lane = tid & 63;
  const int lr = lane & 15, lk = lane >> 4;
  const int n0 = blockIdx.x * 256;
  const int ksb = blockIdx.y;
  const int kbase = ksb * KCH2;
  const bf16* vb = (ksb < 8) ? pvb : mvb;
  const int kcol0 = (ksb < 8) ? kbase : kbase - DALL;

  const int bs = tid >> 2;
  const int bgs = (tid & 3) ^ (bs & 3);

  f32x4 acc[4][4];
  const f32x4 zero = {0.f, 0.f, 0.f, 0.f};
#pragma unroll
  for (int m = 0; m < 4; ++m)
#pragma unroll
    for (int n = 0; n < 4; ++n) acc[m][n] = zero;

  for (int kt = 0; kt < KCH2; kt += 32) {
    __syncthreads();
    {
      const float* src = w1 + (long)(kbase + kt) * DALL + n0 + tid;
      bf16* dst = sAt + tid * 40;
#pragma unroll
      for (int r = 0; r < 32; ++r)
        dst[r] = __float2bfloat16(src[(long)r * DALL]);
    }
    async_copy16((char*)sBt + tid * 16,
                 vb + (long)bs * DALL + kcol0 + kt + bgs * 8);
    __syncthreads();
    bf16x8 af[4], bfr[4];
#pragma unroll
    for (int m = 0; m < 4; ++m)
      af[m] = *(const bf16x8*)((const char*)sAt +
                               ((wid * 64 + m * 16 + lr) * 40 + lk * 8) * 2);
#pragma unroll
    for (int n = 0; n < 4; ++n) {
      const int s = n * 16 + lr;
      bfr[n] = *(const bf16x8*)((const char*)sBt + s * 64 + ((lk ^ (s & 3)) << 4));
    }
#pragma unroll
    for (int m = 0; m < 4; ++m)
#pragma unroll
      for (int n = 0; n < 4; ++n)
        acc[m][n] =
            __builtin_amdgcn_mfma_f32_16x16x32_bf16(af[m], bfr[n], acc[m][n], 0, 0, 0);
  }
#pragma unroll
  for (int m = 0; m < 4; ++m)
#pragma unroll
    for (int n = 0; n < 4; ++n)
#pragma unroll
      for (int j = 0; j < 4; ++j) {
        const int gn = n0 + wid * 64 + m * 16 + lk * 4 + j;
        const int s = n * 16 + lr;
        part[((long)ksb * DALL + gn) * 64 + s] = acc[m][n][j];
      }
}

// ---------------- reduce K-split partials -> CVt bf16 [3584][128] ----------
__global__ __launch_bounds__(256)
void reduce_cvt(const float* __restrict__ part, bf16* __restrict__ cvt) {
  const long i4 = ((long)blockIdx.x * 256 + threadIdx.x) * 4;
  const int n = (int)(i4 >> 7), sc = (int)(i4 & 127);
  const int half = sc >> 6, s0 = sc & 63;
  f32x4 s = {0.f, 0.f, 0.f, 0.f};
#pragma unroll
  for (int j = 0; j < 8; ++j)
    s += *(const f32x4*)(part + ((long)(half * 8 + j) * DALL + n) * 64 + s0);
#pragma unroll
  for (int k = 0; k < 4; ++k) cvt[i4 + k] = __float2bfloat16(s[k]);
}

// ---------------- 128x128 2-barrier GEMM (thin K=128) ----------------------
template <int OUT_BF16, int ADD_BIAS>
__global__ __launch_bounds__(256)
void gemm_bt(const bf16* __restrict__ A, int lda, const bf16* __restrict__ Bt,
             void* __restrict__ Cout, int ldc, int col_off,
             const float* __restrict__ bias, int K) {
  __shared__ __align__(16) bf16 sA[128 * 32];
  __shared__ __align__(16) bf16 sB[128 * 32];
  const int tid = threadIdx.x;
  const int wid = tid >> 6, lane = tid & 63;
  const int lr = lane & 15, lk = lane >> 4;
  const int col0 = blockIdx.x * 128, row0 = blockIdx.y * 128;
  const int wrow = (wid >> 1) * 64, wcol = (wid & 1) * 64;
  const int ea = tid * 8;
  const int ra = ea >> 5, ca = ea & 31;

  f32x4 acc[4][4];
  const f32x4 zero = {0.f, 0.f, 0.f, 0.f};
#pragma unroll
  for (int m = 0; m < 4; ++m)
#pragma unroll
    for (int n = 0; n < 4; ++n) acc[m][n] = zero;

  const long aBase = (long)row0 * lda;
  const long bBase = (long)col0 * K;
  char* sAb = (char*)sA;
  char* sBb = (char*)sB;
  const int wOff = wid * 1024;

  for (int kt = 0; kt < K; kt += 32) {
    __syncthreads();
#pragma unroll
    for (int i = 0; i < 2; ++i) {
      async_copy16(sAb + i * 4096 + wOff,
                   A + aBase + (long)(ra + i * 64) * lda + kt + ca);
      async_copy16(sBb + i * 4096 + wOff,
                   Bt + bBase + (long)(ra + i * 64) * K + kt + ca);
    }
    __syncthreads();
    bf16x8 af[4], bfr[4];
    const bf16x8* pA = (const bf16x8*)sA;
    const bf16x8* pB = (const bf16x8*)sB;
#pragma unroll
    for (int m = 0; m < 4; ++m) af[m] = pA[(wrow + m * 16 + lr) * 4 + lk];
#pragma unroll
    for (int n = 0; n < 4; ++n) bfr[n] = pB[(wcol + n * 16 + lr) * 4 + lk];
#pragma unroll
    for (int m = 0; m < 4; ++m)
#pragma unroll
      for (int n = 0; n < 4; ++n)
        acc[m][n] =
            __builtin_amdgcn_mfma_f32_16x16x32_bf16(af[m], bfr[n], acc[m][n], 0, 0, 0);
  }
#pragma unroll
  for (int m = 0; m < 4; ++m) {
#pragma unroll
    for (int n = 0; n < 4; ++n) {
      const int gcl = col0 + wcol + n * 16 + lr;
      const float bia = ADD_BIAS ? bias[gcl] : 0.f;
#pragma unroll
      for (int j = 0; j < 4; ++j) {
        const int gr = row0 + wrow + m * 16 + lk * 4 + j;
        const float v = acc[m][n][j] + bia;
        const long off = (long)gr * ldc + col_off + gcl;
        if (OUT_BF16)
          ((bf16*)Cout)[off] = __float2bfloat16(v);
        else
          ((float*)Cout)[off] = v;
      }
    }
  }
}

// ---------------- LayerNorm + exact GELU, bf16 in -> bf16 out --------------
__global__ __launch_bounds__(256)
void ln_gelu_kernel(const bf16* __restrict__ h, const float* __restrict__ g,
                    const float* __restrict__ bb, bf16* __restrict__ h2) {
  const int row = blockIdx.x, tid = threadIdx.x;
  const bf16* x = h + (long)row * DALL;
  float v[14];
  float s1 = 0.f, s2 = 0.f;
#pragma unroll
  for (int i = 0; i < 14; ++i) {
    v[i] = __bfloat162float(x[i * 256 + tid]);
    s1 += v[i];
    s2 += v[i] * v[i];
  }
#pragma unroll
  for (int m = 32; m; m >>= 1) {
    s1 += __shfl_xor(s1, m);
    s2 += __shfl_xor(s2, m);
  }
  __shared__ float r1[4], r2[4];
  const int wid = tid >> 6, lane = tid & 63;
  if (lane == 0) {
    r1[wid] = s1;
    r2[wid] = s2;
  }
  __syncthreads();
  s1 = r1[0] + r1[1] + r1[2] + r1[3];
  s2 = r2[0] + r2[1] + r2[2] + r2[3];
  const float mean = s1 * (1.f / DALL);
  const float var = s2 * (1.f / DALL) - mean * mean;
  const float rstd = rsqrtf(var + 1e-5f);
#pragma unroll
  for (int i = 0; i < 14; ++i) {
    const int c = i * 256 + tid;
    const float y = (v[i] - mean) * rstd * g[c] + bb[c];
    const float ge = 0.5f * y * (1.f + erff(y * 0.7071067811865475f));
    h2[(long)row * DALL + c] = __float2bfloat16(ge);
  }
}

// ---------------- per-pair GEMM (K=256) + LayerNorm epilogue ---------------
__global__ __launch_bounds__(256)
void pair_final(const bf16* __restrict__ psb, const bf16* __restrict__ fusedb,
                const bf16* __restrict__ pwT, const float* __restrict__ pb,
                const float* __restrict__ lng, const float* __restrict__ lnb,
                float* __restrict__ out) {
  __shared__ __align__(16) bf16 sA[128 * 32];
  __shared__ __align__(16) bf16 sB[128 * 32];
  const int tid = threadIdx.x, wid = tid >> 6, lane = tid & 63;
  const int lr = lane & 15, lk = lane >> 4;
  const int p = blockIdx.y, row0 = blockIdx.x * 128;
  const int ea = tid * 8, ra = ea >> 5, ca = ea & 31;

  f32x4 acc[2][8];
  const f32x4 zero = {0.f, 0.f, 0.f, 0.f};
#pragma unroll
  for (int m = 0; m < 2; ++m)
#pragma unroll
    for (int n = 0; n < 8; ++n) acc[m][n] = zero;

  const bf16* pwp = pwT + (long)p * (PDIM * MDIM);
  char* sAb = (char*)sA;
  char* sBb = (char*)sB;
  const int wOff = wid * 1024;

  for (int kt = 0; kt < MDIM; kt += 32) {
    __syncthreads();
    const bf16* Asrc = (kt < PDIM) ? psb : fusedb;
    const int kc = kt & (PDIM - 1);
#pragma unroll
    for (int i = 0; i < 2; ++i) {
      async_copy16(sAb + i * 4096 + wOff,
                   Asrc + (long)(row0 + ra + i * 64) * DALL + p * PDIM + kc + ca);
      async_copy16(sBb + i * 4096 + wOff, pwp + (ra + i * 64) * MDIM + kt + ca);
    }
    __syncthreads();
    bf16x8 af[2], bfr[8];
    const bf16x8* pA = (const bf16x8*)sA;
    const bf16x8* pB = (const bf16x8*)sB;
#pragma unroll
    for (int m = 0; m < 2; ++m) af[m] = pA[(wid * 32 + m * 16 + lr) * 4 + lk];
#pragma unroll
    for (int n = 0; n < 8; ++n) bfr[n] = pB[(n * 16 + lr) * 4 + lk];
#pragma unroll
    for (int m = 0; m < 2; ++m)
#pragma unroll
      for (int n = 0; n < 8; ++n)
        acc[m][n] =
            __builtin_amdgcn_mfma_f32_16x16x32_bf16(af[m], bfr[n], acc[m][n], 0, 0, 0);
  }
  float g_[8], b_[8], pb_[8];
#pragma unroll
  for (int n = 0; n < 8; ++n) {
    const int c = n * 16 + lr;
    g_[n] = lng[p * PDIM + c];
    b_[n] = lnb[p * PDIM + c];
    pb_[n] = pb[p * PDIM + c];
  }
#pragma unroll
  for (int m = 0; m < 2; ++m) {
#pragma unroll
    for (int j = 0; j < 4; ++j) {
      float vv[8];
      float s1 = 0.f, s2 = 0.f;
#pragma unroll
      for (int n = 0; n < 8; ++n) {
        vv[n] = acc[m][n][j] + pb_[n];
        s1 += vv[n];
        s2 += vv[n] * vv[n];
      }
#pragma unroll
      for (int msk = 1; msk <= 8; msk <<= 1) {
        s1 += __shfl_xor(s1, msk);
        s2 += __shfl_xor(s2, msk);
      }
      const float mean = s1 * (1.f / 128.f);
      const float var = s2 * (1.f / 128.f) - mean * mean;
      const float rstd = rsqrtf(var + 1e-5f);
      const int gr = row0 + wid * 32 + m * 16 + lk * 4 + j;
      float* orow = out + ((long)gr * NPAIR + p) * PDIM;
#pragma unroll
      for (int n = 0; n < 8; ++n)
        orow[n * 16 + lr] = (vv[n] - mean) * rstd * g_[n] + b_[n];
    }
  }
}

// ---------------------------------------------------------------------------
extern "C" void kernel_launch(void* const* d_in, const int* in_sizes, int n_in,
                              void* d_out, int out_size, void* d_ws, size_t ws_size,
                              hipStream_t stream) {
  (void)in_sizes; (void)n_in; (void)out_size; (void)ws_size;
  const float* ps   = (const float*)d_in[0];
  const float* mac  = (const float*)d_in[1];
  const float* pkey = (const float*)d_in[2];
  const float* pval = (const float*)d_in[3];
  const float* mkey = (const float*)d_in[4];
  const float* mval = (const float*)d_in[5];
  const float* w1   = (const float*)d_in[6];
  const float* b1   = (const float*)d_in[7];
  const float* lng1 = (const float*)d_in[8];
  const float* lnb1 = (const float*)d_in[9];
  const float* w2   = (const float*)d_in[10];
  const float* b2   = (const float*)d_in[11];
  const float* pw   = (const float*)d_in[12];
  const float* pb   = (const float*)d_in[13];
  const float* plng = (const float*)d_in[14];
  const float* plnb = (const float*)d_in[15];
  float* out = (float*)d_out;

  char* w = (char*)d_ws;
  size_t off = 0;
  auto carve = [&](size_t bytes) {
    char* pp = w + off;
    off += (bytes + 255) & ~(size_t)255;
    return pp;
  };
  bf16* psb   = (bf16*)carve((size_t)B_SZ * DALL * 2);
  bf16* w2t   = (bf16*)carve((size_t)(DALL + 32) * DALL * 2);  // +32 pad rows
  bf16* pvb   = (bf16*)carve((size_t)NSLOT * DALL * 2);
  bf16* mvb   = (bf16*)carve((size_t)NSLOT * DALL * 2);
  bf16* pwTb  = (bf16*)carve((size_t)NPAIR * PDIM * MDIM * 2);
  bf16* att   = (bf16*)carve((size_t)B_SZ * 128 * 2);
  bf16* cvt   = (bf16*)carve((size_t)DALL * 128 * 2);
  float* part = (float*)carve((size_t)KS2 * DALL * 64 * 4);
  bf16* hpreb = (bf16*)carve((size_t)B_SZ * DALL * 2);
  bf16* h2    = (bf16*)carve((size_t)B_SZ * DALL * 2);
  bf16* fusedb = hpreb;  // alias: hpreb last read by ln_gelu

  conv2_kernel<<<dim3(NSLOT * DALL / 2048, 2), 256, 0, stream>>>(pval, mval, pvb, mvb);
  tconv_kernel<<<dim3(DALL / 32, DALL / 32, 1), 256, 0, stream>>>(w2, w2t, DALL, DALL, 0, 0);
  tconv_kernel<<<dim3(PDIM / 32, MDIM / 32, NPAIR), 256, 0, stream>>>(
      pw, pwTb, MDIM, PDIM, MDIM * PDIM, MDIM * PDIM);
  // ps->bf16 + mean + softmax (fused)
  prep_kernel<<<dim3(B_SZ), 256, 0, stream>>>(ps, mac, pkey, mkey, psb, att);
  // rank-128 factor directly from fp32 w1
  precompute_direct<<<dim3(DALL / 256, KS2), 256, 0, stream>>>(w1, pvb, mvb, part);
  reduce_cvt<<<dim3(DALL * 128 / 1024), 256, 0, stream>>>(part, cvt);
  // thin GEMM: hpre = att(4096x128) @ CVt^T + b1 -> bf16
  gemm_bt<1, 1><<<dim3(DALL / 128, B_SZ / 128), 256, 0, stream>>>(
      att, 128, cvt, hpreb, DALL, 0, b1, 128);
  ln_gelu_kernel<<<dim3(B_SZ), 256, 0, stream>>>(hpreb, lng1, lnb1, h2);
  // GEMM2: (4096 x 3584) @ (3584 x 3584)^T -> bf16 fused, full 256-block grid
  gemm224<<<dim3(256), 512, 0, stream>>>(h2, w2t, fusedb, b2);
  pair_final<<<dim3(B_SZ / 128, NPAIR), 256, 0, stream>>>(
      psb, fusedb, pwTb, pb, plng, plnb, out);
}